// Round 2
// baseline (1399.049 us; speedup 1.0000x reference)
//
#include <hip/hip_runtime.h>
#include <hip/hip_bf16.h>

#define NPTS 500000
#define NBINS 32768  // 32^3 Morton bins

using bf16 = __hip_bfloat16;

// ---------------------------------------------------------------------------
// Keys cubic conv weights, a = -0.75, taps at offsets [-1,0,1,2], t in [0,1)
// ---------------------------------------------------------------------------
__device__ __forceinline__ void cubic_w(float t, float w[4]) {
  const float a = -0.75f;
  const float t1 = t + 1.0f;
  w[0] = ((a * t1 - 5.0f * a) * t1 + 8.0f * a) * t1 - 4.0f * a;
  w[1] = ((a + 2.0f) * t - (a + 3.0f)) * t * t + 1.0f;
  const float u = 1.0f - t;
  w[2] = ((a + 2.0f) * u - (a + 3.0f)) * u * u + 1.0f;
  const float t2 = 2.0f - t;
  w[3] = ((a * t2 - 5.0f * a) * t2 + 8.0f * a) * t2 - 4.0f * a;
}

// ---------------------------------------------------------------------------
// Transpose (C,H,W) fp32 -> (H*W, C) bf16, 3 planes batched on blockIdx.y.
// ---------------------------------------------------------------------------
__global__ __launch_bounds__(256) void transpose_chw_hwc_bf16(
    const float* __restrict__ p0, const float* __restrict__ p1,
    const float* __restrict__ p2, bf16* __restrict__ dst, int HW) {
  __shared__ float lds[64][65];
  const float* src = (blockIdx.y == 0) ? p0 : ((blockIdx.y == 1) ? p1 : p2);
  bf16* out = dst + (size_t)blockIdx.y * (size_t)HW * 64;
  const int pixBase = blockIdx.x * 64;
  const int tid = threadIdx.x;
  const int lane = tid & 63;
  const int quad = tid >> 6;
#pragma unroll
  for (int k = 0; k < 16; ++k) {
    const int c = k * 4 + quad;
    lds[c][lane] = src[(size_t)c * HW + pixBase + lane];
  }
  __syncthreads();
#pragma unroll
  for (int k = 0; k < 16; ++k) {
    const int pp = k * 4 + quad;
    out[(size_t)(pixBase + pp) * 64 + lane] = __float2bfloat16(lds[lane][pp]);
  }
}

// ---------------------------------------------------------------------------
// Morton binning: count -> scan -> scatter
// ---------------------------------------------------------------------------
__device__ __forceinline__ unsigned spread3(unsigned v) {
  return (v & 1u) | ((v & 2u) << 2) | ((v & 4u) << 4) | ((v & 8u) << 6) |
         ((v & 16u) << 8);
}

__device__ __forceinline__ int bin_of(float cx, float cy, float cz) {
  int xq = (int)((cx + 1.0f) * 16.0f);
  int yq = (int)((cy + 1.0f) * 16.0f);
  int zq = (int)((cz + 1.0f) * 16.0f);
  xq = xq < 0 ? 0 : (xq > 31 ? 31 : xq);
  yq = yq < 0 ? 0 : (yq > 31 ? 31 : yq);
  zq = zq < 0 ? 0 : (zq > 31 ? 31 : zq);
  return (int)(spread3((unsigned)xq) | (spread3((unsigned)yq) << 1) |
               (spread3((unsigned)zq) << 2));
}

__global__ __launch_bounds__(256) void bin_count(
    const float* __restrict__ coords, int* __restrict__ counts) {
  const int pt = blockIdx.x * 256 + threadIdx.x;
  if (pt >= NPTS) return;
  const int b = bin_of(coords[pt * 3], coords[pt * 3 + 1], coords[pt * 3 + 2]);
  atomicAdd(&counts[b], 1);
}

__global__ __launch_bounds__(1024) void bin_scan(
    const int* __restrict__ counts, int* __restrict__ cursor) {
  __shared__ int lds[1024];
  const int t = threadIdx.x;
  const int base = t * 32;
  int s = 0;
#pragma unroll
  for (int i = 0; i < 32; ++i) s += counts[base + i];
  lds[t] = s;
  __syncthreads();
  int own = s;
  for (int off = 1; off < 1024; off <<= 1) {
    int v = (t >= off) ? lds[t - off] : 0;
    __syncthreads();
    lds[t] += v;
    __syncthreads();
  }
  int run = lds[t] - own;  // exclusive prefix of this thread's chunk
#pragma unroll
  for (int i = 0; i < 32; ++i) {
    cursor[base + i] = run;
    run += counts[base + i];
  }
}

__global__ __launch_bounds__(256) void bin_scatter(
    const float* __restrict__ coords, int* __restrict__ cursor,
    int* __restrict__ sidx) {
  const int pt = blockIdx.x * 256 + threadIdx.x;
  if (pt >= NPTS) return;
  const int b = bin_of(coords[pt * 3], coords[pt * 3 + 1], coords[pt * 3 + 2]);
  const int pos = atomicAdd(&cursor[b], 1);
  sidx[pos] = pt;
}

// ---------------------------------------------------------------------------
// Bicubic sample from transposed (H,W,C) bf16 plane; 8 lanes/point, 8 ch/lane.
// ---------------------------------------------------------------------------
__device__ __forceinline__ void sample_plane_bf16(
    const ushort* __restrict__ plane, int W, float gx, float gy, int cg,
    float acc[8]) {
  const float x = (gx + 1.0f) * 0.5f * (float)(W - 1);
  const float y = (gy + 1.0f) * 0.5f * (float)(W - 1);
  const float x0f = floorf(x), y0f = floorf(y);
  float wx[4], wy[4];
  cubic_w(x - x0f, wx);
  cubic_w(y - y0f, wy);
  const int x0 = (int)x0f, y0 = (int)y0f;
  int ix[4], iy[4];
#pragma unroll
  for (int i = 0; i < 4; ++i) {
    int xi = x0 - 1 + i;
    ix[i] = xi < 0 ? 0 : (xi > W - 1 ? W - 1 : xi);
    int yi = y0 - 1 + i;
    iy[i] = yi < 0 ? 0 : (yi > W - 1 ? W - 1 : yi);
  }
#pragma unroll
  for (int j = 0; j < 4; ++j) {
    const ushort* rbase = plane + (size_t)iy[j] * W * 64 + cg * 8;
    float row[8];
#pragma unroll
    for (int k = 0; k < 8; ++k) row[k] = 0.0f;
#pragma unroll
    for (int i = 0; i < 4; ++i) {
      const uint4 v = *reinterpret_cast<const uint4*>(rbase + ix[i] * 64);
      const unsigned u[4] = {v.x, v.y, v.z, v.w};
#pragma unroll
      for (int k = 0; k < 4; ++k) {
        row[2 * k] += wx[i] * __uint_as_float(u[k] << 16);
        row[2 * k + 1] += wx[i] * __uint_as_float(u[k] & 0xFFFF0000u);
      }
    }
#pragma unroll
    for (int k = 0; k < 8; ++k) acc[k] += wy[j] * row[k];
  }
}

__global__ __launch_bounds__(256) void sample_sorted(
    const float* __restrict__ coords, const ushort* __restrict__ tp,
    const int* __restrict__ sidx, float* __restrict__ out, int nwg) {
  // bijective XCD-chunk swizzle: consecutive work-chunks land on one XCD's L2
  const int orig = blockIdx.x;
  const int q = nwg >> 3, r = nwg & 7;
  const int xcd = orig & 7, idx = orig >> 3;
  const int wg = (xcd < r ? xcd * (q + 1) : r * (q + 1) + (xcd - r) * q) + idx;

  const int t = wg * 256 + (int)threadIdx.x;
  const int slot = t >> 3;
  const int cg = t & 7;  // 8 channels per lane
  if (slot >= NPTS) return;
  const int pt = sidx[slot];
  const float cx = (coords[pt * 3 + 0] + 1.0f) * 0.5f;
  const float cy = (coords[pt * 3 + 1] + 1.0f) * 0.5f;
  const float cz = (coords[pt * 3 + 2] + 1.0f) * 0.5f;

  const size_t sbase[3] = {0, 12582912, 15728640};  // bf16 element offsets
  const size_t spsz[3] = {4194304, 1048576, 262144};
  const int sw[3] = {256, 128, 64};
  float* optr = out + (size_t)pt * 192 + cg * 8;
#pragma unroll
  for (int s = 0; s < 3; ++s) {
    const int W = sw[s];
    const size_t psz = spsz[s];
    const ushort* bxy = tp + sbase[s];
    float acc[8];
#pragma unroll
    for (int k = 0; k < 8; ++k) acc[k] = 0.0f;
    sample_plane_bf16(bxy, W, cx, cy, cg, acc);
    sample_plane_bf16(bxy + psz, W, cy, cz, cg, acc);
    sample_plane_bf16(bxy + 2 * psz, W, cx, cz, cg, acc);
    *reinterpret_cast<float4*>(optr + s * 64) =
        make_float4(acc[0], acc[1], acc[2], acc[3]);
    *reinterpret_cast<float4*>(optr + s * 64 + 4) =
        make_float4(acc[4], acc[5], acc[6], acc[7]);
  }
}

// ---------------------------------------------------------------------------
// Fallback: fp32 direct from (C,H,W) if workspace too small.
// ---------------------------------------------------------------------------
__device__ __forceinline__ void sample_acc_chw(const float* __restrict__ plane,
                                               int W, float gx, float gy,
                                               int cg, float4& acc) {
  const float x = (gx + 1.0f) * 0.5f * (float)(W - 1);
  const float y = (gy + 1.0f) * 0.5f * (float)(W - 1);
  const float x0f = floorf(x), y0f = floorf(y);
  float wx[4], wy[4];
  cubic_w(x - x0f, wx);
  cubic_w(y - y0f, wy);
  const int x0 = (int)x0f, y0 = (int)y0f;
  int ix[4], iy[4];
#pragma unroll
  for (int i = 0; i < 4; ++i) {
    int xi = x0 - 1 + i;
    ix[i] = xi < 0 ? 0 : (xi > W - 1 ? W - 1 : xi);
    int yi = y0 - 1 + i;
    iy[i] = yi < 0 ? 0 : (yi > W - 1 ? W - 1 : yi);
  }
  const size_t HW = (size_t)W * W;
  float r[4] = {acc.x, acc.y, acc.z, acc.w};
#pragma unroll
  for (int cc = 0; cc < 4; ++cc) {
    const float* pc = plane + (size_t)(cg * 4 + cc) * HW;
    float a = 0.f;
#pragma unroll
    for (int j = 0; j < 4; ++j) {
      const float* rb = pc + (size_t)iy[j] * W;
      float row = 0.f;
#pragma unroll
      for (int i = 0; i < 4; ++i) row += wx[i] * rb[ix[i]];
      a += wy[j] * row;
    }
    r[cc] += a;
  }
  acc = make_float4(r[0], r[1], r[2], r[3]);
}

__global__ __launch_bounds__(256) void sample_fallback(
    const float* __restrict__ coords, const float* __restrict__ px0,
    const float* __restrict__ py0, const float* __restrict__ pz0,
    const float* __restrict__ px1, const float* __restrict__ py1,
    const float* __restrict__ pz1, const float* __restrict__ px2,
    const float* __restrict__ py2, const float* __restrict__ pz2,
    float* __restrict__ out) {
  const int t = blockIdx.x * 256 + threadIdx.x;
  const int pt = t >> 4;
  const int cg = t & 15;
  if (pt >= NPTS) return;
  const float cx = (coords[pt * 3 + 0] + 1.0f) * 0.5f;
  const float cy = (coords[pt * 3 + 1] + 1.0f) * 0.5f;
  const float cz = (coords[pt * 3 + 2] + 1.0f) * 0.5f;
  const float* xs[3] = {px0, px1, px2};
  const float* ys[3] = {py0, py1, py2};
  const float* zs[3] = {pz0, pz1, pz2};
  const int sw[3] = {256, 128, 64};
  float* optr = out + (size_t)pt * 192 + cg * 4;
#pragma unroll
  for (int s = 0; s < 3; ++s) {
    const int W = sw[s];
    float4 acc = make_float4(0.f, 0.f, 0.f, 0.f);
    sample_acc_chw(xs[s], W, cx, cy, cg, acc);
    sample_acc_chw(ys[s], W, cy, cz, cg, acc);
    sample_acc_chw(zs[s], W, cx, cz, cg, acc);
    *reinterpret_cast<float4*>(optr + s * 64) = acc;
  }
}

// ---------------------------------------------------------------------------
extern "C" void kernel_launch(void* const* d_in, const int* in_sizes, int n_in,
                              void* d_out, int out_size, void* d_ws,
                              size_t ws_size, hipStream_t stream) {
  const float* coords = (const float*)d_in[0];
  const float* px0 = (const float*)d_in[1];
  const float* py0 = (const float*)d_in[2];
  const float* pz0 = (const float*)d_in[3];
  const float* px1 = (const float*)d_in[4];
  const float* py1 = (const float*)d_in[5];
  const float* pz1 = (const float*)d_in[6];
  const float* px2 = (const float*)d_in[7];
  const float* py2 = (const float*)d_in[8];
  const float* pz2 = (const float*)d_in[9];
  float* out = (float*)d_out;

  // ws layout (bytes): bf16 planes [0, 33030144), counts, cursor, sidx
  const size_t TP_BYTES = 33030144;
  const size_t CNT_OFF = TP_BYTES;               // 131072 B
  const size_t CUR_OFF = CNT_OFF + 131072;       // 131072 B
  const size_t IDX_OFF = CUR_OFF + 131072;       // 2,000,000 B
  const size_t NEEDED = IDX_OFF + 2000000;

  if (ws_size >= NEEDED) {
    bf16* tp = (bf16*)d_ws;
    int* counts = (int*)((char*)d_ws + CNT_OFF);
    int* cursor = (int*)((char*)d_ws + CUR_OFF);
    int* sidx = (int*)((char*)d_ws + IDX_OFF);

    transpose_chw_hwc_bf16<<<dim3(65536 / 64, 3), 256, 0, stream>>>(
        px0, py0, pz0, tp + 0, 65536);
    transpose_chw_hwc_bf16<<<dim3(16384 / 64, 3), 256, 0, stream>>>(
        px1, py1, pz1, tp + 12582912, 16384);
    transpose_chw_hwc_bf16<<<dim3(4096 / 64, 3), 256, 0, stream>>>(
        px2, py2, pz2, tp + 15728640, 4096);

    hipMemsetAsync(counts, 0, NBINS * sizeof(int), stream);
    const int pblocks = (NPTS + 255) / 256;
    bin_count<<<pblocks, 256, 0, stream>>>(coords, counts);
    bin_scan<<<1, 1024, 0, stream>>>(counts, cursor);
    bin_scatter<<<pblocks, 256, 0, stream>>>(coords, cursor, sidx);

    const int nwg = (NPTS * 8) / 256;  // 15625, exact
    sample_sorted<<<nwg, 256, 0, stream>>>(coords, (const ushort*)tp, sidx,
                                           out, nwg);
  } else {
    const int sample_blocks = (NPTS * 16 + 255) / 256;
    sample_fallback<<<sample_blocks, 256, 0, stream>>>(
        coords, px0, py0, pz0, px1, py1, pz1, px2, py2, pz2, out);
  }
}

// Round 3
// 610.484 us; speedup vs baseline: 2.2917x; 2.2917x over previous
//
#include <hip/hip_runtime.h>
#include <hip/hip_bf16.h>

#define NPTS 500000
#define NBINS 32768  // 32^3 Morton bins

using bf16 = __hip_bfloat16;

// ---------------------------------------------------------------------------
// Keys cubic conv weights, a = -0.75, taps at offsets [-1,0,1,2], t in [0,1)
// ---------------------------------------------------------------------------
__device__ __forceinline__ void cubic_w(float t, float w[4]) {
  const float a = -0.75f;
  const float t1 = t + 1.0f;
  w[0] = ((a * t1 - 5.0f * a) * t1 + 8.0f * a) * t1 - 4.0f * a;
  w[1] = ((a + 2.0f) * t - (a + 3.0f)) * t * t + 1.0f;
  const float u = 1.0f - t;
  w[2] = ((a + 2.0f) * u - (a + 3.0f)) * u * u + 1.0f;
  const float t2 = 2.0f - t;
  w[3] = ((a * t2 - 5.0f * a) * t2 + 8.0f * a) * t2 - 4.0f * a;
}

// ---------------------------------------------------------------------------
// Transpose (C,H,W) fp32 -> (H*W, C) bf16, 3 planes batched on blockIdx.y.
// ---------------------------------------------------------------------------
__global__ __launch_bounds__(256) void transpose_chw_hwc_bf16(
    const float* __restrict__ p0, const float* __restrict__ p1,
    const float* __restrict__ p2, bf16* __restrict__ dst, int HW) {
  __shared__ float lds[64][65];
  const float* src = (blockIdx.y == 0) ? p0 : ((blockIdx.y == 1) ? p1 : p2);
  bf16* out = dst + (size_t)blockIdx.y * (size_t)HW * 64;
  const int pixBase = blockIdx.x * 64;
  const int tid = threadIdx.x;
  const int lane = tid & 63;
  const int quad = tid >> 6;
#pragma unroll
  for (int k = 0; k < 16; ++k) {
    const int c = k * 4 + quad;
    lds[c][lane] = src[(size_t)c * HW + pixBase + lane];
  }
  __syncthreads();
#pragma unroll
  for (int k = 0; k < 16; ++k) {
    const int pp = k * 4 + quad;
    out[(size_t)(pixBase + pp) * 64 + lane] = __float2bfloat16(lds[lane][pp]);
  }
}

// ---------------------------------------------------------------------------
// Morton binning: count -> scan -> scatter (scatter also pre-gathers coords)
// ---------------------------------------------------------------------------
__device__ __forceinline__ unsigned spread3(unsigned v) {
  return (v & 1u) | ((v & 2u) << 2) | ((v & 4u) << 4) | ((v & 8u) << 6) |
         ((v & 16u) << 8);
}

__device__ __forceinline__ int bin_of(float cx, float cy, float cz) {
  int xq = (int)((cx + 1.0f) * 16.0f);
  int yq = (int)((cy + 1.0f) * 16.0f);
  int zq = (int)((cz + 1.0f) * 16.0f);
  xq = xq < 0 ? 0 : (xq > 31 ? 31 : xq);
  yq = yq < 0 ? 0 : (yq > 31 ? 31 : yq);
  zq = zq < 0 ? 0 : (zq > 31 ? 31 : zq);
  return (int)(spread3((unsigned)xq) | (spread3((unsigned)yq) << 1) |
               (spread3((unsigned)zq) << 2));
}

__global__ __launch_bounds__(256) void bin_count(
    const float* __restrict__ coords, int* __restrict__ counts) {
  const int pt = blockIdx.x * 256 + threadIdx.x;
  if (pt >= NPTS) return;
  const int b = bin_of(coords[pt * 3], coords[pt * 3 + 1], coords[pt * 3 + 2]);
  atomicAdd(&counts[b], 1);
}

__global__ __launch_bounds__(1024) void bin_scan(
    const int* __restrict__ counts, int* __restrict__ cursor) {
  __shared__ int lds[1024];
  const int t = threadIdx.x;
  const int base = t * 32;
  int s = 0;
#pragma unroll
  for (int i = 0; i < 32; ++i) s += counts[base + i];
  lds[t] = s;
  __syncthreads();
  int own = s;
  for (int off = 1; off < 1024; off <<= 1) {
    int v = (t >= off) ? lds[t - off] : 0;
    __syncthreads();
    lds[t] += v;
    __syncthreads();
  }
  int run = lds[t] - own;
#pragma unroll
  for (int i = 0; i < 32; ++i) {
    cursor[base + i] = run;
    run += counts[base + i];
  }
}

__global__ __launch_bounds__(256) void bin_scatter(
    const float* __restrict__ coords, int* __restrict__ cursor,
    float4* __restrict__ spts) {
  const int pt = blockIdx.x * 256 + threadIdx.x;
  if (pt >= NPTS) return;
  const float x = coords[pt * 3], y = coords[pt * 3 + 1], z = coords[pt * 3 + 2];
  const int b = bin_of(x, y, z);
  const int pos = atomicAdd(&cursor[b], 1);
  spts[pos] = make_float4(x, y, z, __int_as_float(pt));
}

// ---------------------------------------------------------------------------
// Per-axis tap indices + weights (reference arithmetic order preserved)
// ---------------------------------------------------------------------------
__device__ __forceinline__ void axis_prep(float v, int W, int idx[4],
                                          float w[4]) {
  const float c = (v + 1.0f) * 0.5f;          // coords -> [0,1]
  const float x = (c + 1.0f) * 0.5f * (float)(W - 1);  // grid_sample unnorm
  const float x0f = floorf(x);
  cubic_w(x - x0f, w);
  const int x0 = (int)x0f;
#pragma unroll
  for (int i = 0; i < 4; ++i) {
    int xi = x0 - 1 + i;
    idx[i] = xi < 0 ? 0 : (xi > W - 1 ? W - 1 : xi);
  }
}

// col = first grid coord (W dim), row = second (H dim): plane[:, row, col]
__device__ __forceinline__ void samp4(const ushort* __restrict__ plane, int W,
                                      const int ci[4], const float cw[4],
                                      const int ri[4], const float rw[4],
                                      int cg, float acc[4]) {
#pragma unroll
  for (int j = 0; j < 4; ++j) {
    const ushort* rbase = plane + (size_t)ri[j] * W * 64 + cg * 4;
    float row[4] = {0.f, 0.f, 0.f, 0.f};
#pragma unroll
    for (int i = 0; i < 4; ++i) {
      const uint2 v = *reinterpret_cast<const uint2*>(rbase + ci[i] * 64);
      row[0] += cw[i] * __uint_as_float(v.x << 16);
      row[1] += cw[i] * __uint_as_float(v.x & 0xFFFF0000u);
      row[2] += cw[i] * __uint_as_float(v.y << 16);
      row[3] += cw[i] * __uint_as_float(v.y & 0xFFFF0000u);
    }
#pragma unroll
    for (int k = 0; k < 4; ++k) acc[k] += rw[j] * row[k];
  }
}

// ---------------------------------------------------------------------------
// Sample kernel: blockIdx.y = scale; 16 lanes/point x 4 channels each.
// ---------------------------------------------------------------------------
__global__ __launch_bounds__(256, 4) void sample_sorted16(
    const float4* __restrict__ spts, const ushort* __restrict__ tp,
    float* __restrict__ out, int nwgx) {
  // bijective XCD-chunk swizzle within each scale slice
  const int orig = blockIdx.x;
  const int q = nwgx >> 3, r = nwgx & 7;
  const int xcd = orig & 7, idx = orig >> 3;
  const int wg = (xcd < r ? xcd * (q + 1) : r * (q + 1) + (xcd - r) * q) + idx;

  const int t = wg * 256 + (int)threadIdx.x;
  const int slot = t >> 4;
  const int cg = t & 15;  // 4 channels per lane
  if (slot >= NPTS) return;
  const int s = blockIdx.y;

  const float4 P = spts[slot];
  const int pt = __float_as_int(P.w);

  const int W = (s == 0) ? 256 : ((s == 1) ? 128 : 64);
  const size_t base = (s == 0) ? 0 : ((s == 1) ? 12582912 : 15728640);
  const size_t psz = (size_t)W * W * 64;

  float wxa[4], wya[4], wza[4];
  int ixa[4], iya[4], iza[4];
  axis_prep(P.x, W, ixa, wxa);
  axis_prep(P.y, W, iya, wya);
  axis_prep(P.z, W, iza, wza);

  const ushort* b = tp + base;
  float acc[4] = {0.f, 0.f, 0.f, 0.f};
  samp4(b, W, ixa, wxa, iya, wya, cg, acc);            // xy: col=x, row=y
  samp4(b + psz, W, iya, wya, iza, wza, cg, acc);      // yz: col=y, row=z
  samp4(b + 2 * psz, W, ixa, wxa, iza, wza, cg, acc);  // xz: col=x, row=z

  *reinterpret_cast<float4*>(out + (size_t)pt * 192 + s * 64 + cg * 4) =
      make_float4(acc[0], acc[1], acc[2], acc[3]);
}

// ---------------------------------------------------------------------------
// Fallback: fp32 direct from (C,H,W) if workspace too small.
// ---------------------------------------------------------------------------
__device__ __forceinline__ void sample_acc_chw(const float* __restrict__ plane,
                                               int W, float gx, float gy,
                                               int cg, float4& acc) {
  const float x = (gx + 1.0f) * 0.5f * (float)(W - 1);
  const float y = (gy + 1.0f) * 0.5f * (float)(W - 1);
  const float x0f = floorf(x), y0f = floorf(y);
  float wx[4], wy[4];
  cubic_w(x - x0f, wx);
  cubic_w(y - y0f, wy);
  const int x0 = (int)x0f, y0 = (int)y0f;
  int ix[4], iy[4];
#pragma unroll
  for (int i = 0; i < 4; ++i) {
    int xi = x0 - 1 + i;
    ix[i] = xi < 0 ? 0 : (xi > W - 1 ? W - 1 : xi);
    int yi = y0 - 1 + i;
    iy[i] = yi < 0 ? 0 : (yi > W - 1 ? W - 1 : yi);
  }
  const size_t HW = (size_t)W * W;
  float r[4] = {acc.x, acc.y, acc.z, acc.w};
#pragma unroll
  for (int cc = 0; cc < 4; ++cc) {
    const float* pc = plane + (size_t)(cg * 4 + cc) * HW;
    float a = 0.f;
#pragma unroll
    for (int j = 0; j < 4; ++j) {
      const float* rb = pc + (size_t)iy[j] * W;
      float row = 0.f;
#pragma unroll
      for (int i = 0; i < 4; ++i) row += wx[i] * rb[ix[i]];
      a += wy[j] * row;
    }
    r[cc] += a;
  }
  acc = make_float4(r[0], r[1], r[2], r[3]);
}

__global__ __launch_bounds__(256) void sample_fallback(
    const float* __restrict__ coords, const float* __restrict__ px0,
    const float* __restrict__ py0, const float* __restrict__ pz0,
    const float* __restrict__ px1, const float* __restrict__ py1,
    const float* __restrict__ pz1, const float* __restrict__ px2,
    const float* __restrict__ py2, const float* __restrict__ pz2,
    float* __restrict__ out) {
  const int t = blockIdx.x * 256 + threadIdx.x;
  const int pt = t >> 4;
  const int cg = t & 15;
  if (pt >= NPTS) return;
  const float cx = (coords[pt * 3 + 0] + 1.0f) * 0.5f;
  const float cy = (coords[pt * 3 + 1] + 1.0f) * 0.5f;
  const float cz = (coords[pt * 3 + 2] + 1.0f) * 0.5f;
  const float* xs[3] = {px0, px1, px2};
  const float* ys[3] = {py0, py1, py2};
  const float* zs[3] = {pz0, pz1, pz2};
  const int sw[3] = {256, 128, 64};
  float* optr = out + (size_t)pt * 192 + cg * 4;
#pragma unroll
  for (int s = 0; s < 3; ++s) {
    const int W = sw[s];
    float4 acc = make_float4(0.f, 0.f, 0.f, 0.f);
    sample_acc_chw(xs[s], W, cx, cy, cg, acc);
    sample_acc_chw(ys[s], W, cy, cz, cg, acc);
    sample_acc_chw(zs[s], W, cx, cz, cg, acc);
    *reinterpret_cast<float4*>(optr + s * 64) = acc;
  }
}

// ---------------------------------------------------------------------------
extern "C" void kernel_launch(void* const* d_in, const int* in_sizes, int n_in,
                              void* d_out, int out_size, void* d_ws,
                              size_t ws_size, hipStream_t stream) {
  const float* coords = (const float*)d_in[0];
  const float* px0 = (const float*)d_in[1];
  const float* py0 = (const float*)d_in[2];
  const float* pz0 = (const float*)d_in[3];
  const float* px1 = (const float*)d_in[4];
  const float* py1 = (const float*)d_in[5];
  const float* pz1 = (const float*)d_in[6];
  const float* px2 = (const float*)d_in[7];
  const float* py2 = (const float*)d_in[8];
  const float* pz2 = (const float*)d_in[9];
  float* out = (float*)d_out;

  // ws layout (bytes): bf16 planes, counts, cursor, sorted point records
  const size_t TP_BYTES = 33030144;
  const size_t CNT_OFF = TP_BYTES;           // 131072 B
  const size_t CUR_OFF = CNT_OFF + 131072;   // 131072 B
  const size_t PTS_OFF = CUR_OFF + 131072;   // 8,000,000 B
  const size_t NEEDED = PTS_OFF + (size_t)NPTS * 16;

  if (ws_size >= NEEDED) {
    bf16* tp = (bf16*)d_ws;
    int* counts = (int*)((char*)d_ws + CNT_OFF);
    int* cursor = (int*)((char*)d_ws + CUR_OFF);
    float4* spts = (float4*)((char*)d_ws + PTS_OFF);

    transpose_chw_hwc_bf16<<<dim3(65536 / 64, 3), 256, 0, stream>>>(
        px0, py0, pz0, tp + 0, 65536);
    transpose_chw_hwc_bf16<<<dim3(16384 / 64, 3), 256, 0, stream>>>(
        px1, py1, pz1, tp + 12582912, 16384);
    transpose_chw_hwc_bf16<<<dim3(4096 / 64, 3), 256, 0, stream>>>(
        px2, py2, pz2, tp + 15728640, 4096);

    hipMemsetAsync(counts, 0, NBINS * sizeof(int), stream);
    const int pblocks = (NPTS + 255) / 256;
    bin_count<<<pblocks, 256, 0, stream>>>(coords, counts);
    bin_scan<<<1, 1024, 0, stream>>>(counts, cursor);
    bin_scatter<<<pblocks, 256, 0, stream>>>(coords, cursor, spts);

    const int nwgx = (NPTS * 16) / 256;  // 31250, exact
    sample_sorted16<<<dim3(nwgx, 3), 256, 0, stream>>>(spts, (const ushort*)tp,
                                                       out, nwgx);
  } else {
    const int sample_blocks = (NPTS * 16 + 255) / 256;
    sample_fallback<<<sample_blocks, 256, 0, stream>>>(
        coords, px0, py0, pz0, px1, py1, pz1, px2, py2, pz2, out);
  }
}

// Round 4
// 609.049 us; speedup vs baseline: 2.2971x; 1.0024x over previous
//
#include <hip/hip_runtime.h>
#include <hip/hip_fp16.h>

#define NPTS 500000
#define NBINS 32768  // 32^3 Morton bins

// Planes stored fp16, pre-scaled by 1024 (exact pow2); final result * 1/1024.
#define PLANE_SCALE 1024.0f
#define INV_PLANE_SCALE 0.0009765625f

// ---------------------------------------------------------------------------
// Keys cubic conv weights, a = -0.75, taps at offsets [-1,0,1,2], t in [0,1)
// ---------------------------------------------------------------------------
__device__ __forceinline__ void cubic_w(float t, float w[4]) {
  const float a = -0.75f;
  const float t1 = t + 1.0f;
  w[0] = ((a * t1 - 5.0f * a) * t1 + 8.0f * a) * t1 - 4.0f * a;
  w[1] = ((a + 2.0f) * t - (a + 3.0f)) * t * t + 1.0f;
  const float u = 1.0f - t;
  w[2] = ((a + 2.0f) * u - (a + 3.0f)) * u * u + 1.0f;
  const float t2 = 2.0f - t;
  w[3] = ((a * t2 - 5.0f * a) * t2 + 8.0f * a) * t2 - 4.0f * a;
}

// ---------------------------------------------------------------------------
// Transpose (C,H,W) fp32 -> (H*W, C) fp16*1024, 3 planes batched on blockIdx.y
// ---------------------------------------------------------------------------
__global__ __launch_bounds__(256) void transpose_chw_hwc_f16(
    const float* __restrict__ p0, const float* __restrict__ p1,
    const float* __restrict__ p2, __half* __restrict__ dst, int HW) {
  __shared__ float lds[64][65];
  const float* src = (blockIdx.y == 0) ? p0 : ((blockIdx.y == 1) ? p1 : p2);
  __half* out = dst + (size_t)blockIdx.y * (size_t)HW * 64;
  const int pixBase = blockIdx.x * 64;
  const int tid = threadIdx.x;
  const int lane = tid & 63;
  const int quad = tid >> 6;
#pragma unroll
  for (int k = 0; k < 16; ++k) {
    const int c = k * 4 + quad;
    lds[c][lane] = src[(size_t)c * HW + pixBase + lane];
  }
  __syncthreads();
#pragma unroll
  for (int k = 0; k < 16; ++k) {
    const int pp = k * 4 + quad;
    out[(size_t)(pixBase + pp) * 64 + lane] =
        __float2half(lds[lane][pp] * PLANE_SCALE);
  }
}

// ---------------------------------------------------------------------------
// Morton binning: count -> scan -> scatter (scatter also pre-gathers coords)
// ---------------------------------------------------------------------------
__device__ __forceinline__ unsigned spread3(unsigned v) {
  return (v & 1u) | ((v & 2u) << 2) | ((v & 4u) << 4) | ((v & 8u) << 6) |
         ((v & 16u) << 8);
}

__device__ __forceinline__ int bin_of(float cx, float cy, float cz) {
  int xq = (int)((cx + 1.0f) * 16.0f);
  int yq = (int)((cy + 1.0f) * 16.0f);
  int zq = (int)((cz + 1.0f) * 16.0f);
  xq = xq < 0 ? 0 : (xq > 31 ? 31 : xq);
  yq = yq < 0 ? 0 : (yq > 31 ? 31 : yq);
  zq = zq < 0 ? 0 : (zq > 31 ? 31 : zq);
  return (int)(spread3((unsigned)xq) | (spread3((unsigned)yq) << 1) |
               (spread3((unsigned)zq) << 2));
}

__global__ __launch_bounds__(256) void bin_count(
    const float* __restrict__ coords, int* __restrict__ counts) {
  const int pt = blockIdx.x * 256 + threadIdx.x;
  if (pt >= NPTS) return;
  const int b = bin_of(coords[pt * 3], coords[pt * 3 + 1], coords[pt * 3 + 2]);
  atomicAdd(&counts[b], 1);
}

__global__ __launch_bounds__(1024) void bin_scan(
    const int* __restrict__ counts, int* __restrict__ cursor) {
  __shared__ int lds[1024];
  const int t = threadIdx.x;
  const int base = t * 32;
  int s = 0;
#pragma unroll
  for (int i = 0; i < 32; ++i) s += counts[base + i];
  lds[t] = s;
  __syncthreads();
  int own = s;
  for (int off = 1; off < 1024; off <<= 1) {
    int v = (t >= off) ? lds[t - off] : 0;
    __syncthreads();
    lds[t] += v;
    __syncthreads();
  }
  int run = lds[t] - own;
#pragma unroll
  for (int i = 0; i < 32; ++i) {
    cursor[base + i] = run;
    run += counts[base + i];
  }
}

__global__ __launch_bounds__(256) void bin_scatter(
    const float* __restrict__ coords, int* __restrict__ cursor,
    float4* __restrict__ spts) {
  const int pt = blockIdx.x * 256 + threadIdx.x;
  if (pt >= NPTS) return;
  const float x = coords[pt * 3], y = coords[pt * 3 + 1], z = coords[pt * 3 + 2];
  const int b = bin_of(x, y, z);
  const int pos = atomicAdd(&cursor[b], 1);
  spts[pos] = make_float4(x, y, z, __int_as_float(pt));
}

// ---------------------------------------------------------------------------
// Per-axis tap indices + packed-broadcast f16 weights (weight VALUES computed
// in fp32 with the reference arithmetic order, then quantized once).
// ---------------------------------------------------------------------------
__device__ __forceinline__ void axis_prep_h(float v, int W, int idx[4],
                                            __half2 w2[4]) {
  const float c = (v + 1.0f) * 0.5f;                   // coords -> [0,1]
  const float x = (c + 1.0f) * 0.5f * (float)(W - 1);  // grid_sample unnorm
  const float x0f = floorf(x);
  float w[4];
  cubic_w(x - x0f, w);
  const int x0 = (int)x0f;
#pragma unroll
  for (int i = 0; i < 4; ++i) {
    int xi = x0 - 1 + i;
    idx[i] = xi < 0 ? 0 : (xi > W - 1 ? W - 1 : xi);
    w2[i] = __half2half2(__float2half(w[i]));
  }
}

// col = first grid coord (W dim), row = second (H dim): plane[:, row, col]
__device__ __forceinline__ void samp4_h(const ushort* __restrict__ plane, int W,
                                        const int ci[4], const __half2 cw[4],
                                        const int ri[4], const __half2 rw[4],
                                        int cg, __half2 acc[2]) {
#pragma unroll
  for (int j = 0; j < 4; ++j) {
    const ushort* rbase = plane + (size_t)ri[j] * W * 64 + cg * 4;
    __half2 row0 = __float2half2_rn(0.0f);
    __half2 row1 = __float2half2_rn(0.0f);
#pragma unroll
    for (int i = 0; i < 4; ++i) {
      const uint2 v = *reinterpret_cast<const uint2*>(rbase + ci[i] * 64);
      row0 = __hfma2(cw[i], *reinterpret_cast<const __half2*>(&v.x), row0);
      row1 = __hfma2(cw[i], *reinterpret_cast<const __half2*>(&v.y), row1);
    }
    acc[0] = __hfma2(rw[j], row0, acc[0]);
    acc[1] = __hfma2(rw[j], row1, acc[1]);
  }
}

// ---------------------------------------------------------------------------
// Sample kernel: blockIdx.y = scale; 16 lanes/point x 4 channels each.
// ---------------------------------------------------------------------------
__global__ __launch_bounds__(256, 4) void sample_sorted16h(
    const float4* __restrict__ spts, const ushort* __restrict__ tp,
    float* __restrict__ out, int nwgx) {
  // bijective XCD-chunk swizzle within each scale slice
  const int orig = blockIdx.x;
  const int q = nwgx >> 3, r = nwgx & 7;
  const int xcd = orig & 7, idx = orig >> 3;
  const int wg = (xcd < r ? xcd * (q + 1) : r * (q + 1) + (xcd - r) * q) + idx;

  const int t = wg * 256 + (int)threadIdx.x;
  const int slot = t >> 4;
  const int cg = t & 15;  // 4 channels per lane
  if (slot >= NPTS) return;
  const int s = blockIdx.y;

  const float4 P = spts[slot];
  const int pt = __float_as_int(P.w);

  const int W = (s == 0) ? 256 : ((s == 1) ? 128 : 64);
  const size_t base = (s == 0) ? 0 : ((s == 1) ? 12582912 : 15728640);
  const size_t psz = (size_t)W * W * 64;

  __half2 wx2[4], wy2[4], wz2[4];
  int ixa[4], iya[4], iza[4];
  axis_prep_h(P.x, W, ixa, wx2);
  axis_prep_h(P.y, W, iya, wy2);
  axis_prep_h(P.z, W, iza, wz2);

  const ushort* b = tp + base;
  __half2 acc[2] = {__float2half2_rn(0.0f), __float2half2_rn(0.0f)};
  samp4_h(b, W, ixa, wx2, iya, wy2, cg, acc);            // xy: col=x, row=y
  samp4_h(b + psz, W, iya, wy2, iza, wz2, cg, acc);      // yz: col=y, row=z
  samp4_h(b + 2 * psz, W, ixa, wx2, iza, wz2, cg, acc);  // xz: col=x, row=z

  const float2 r0 = __half22float2(acc[0]);
  const float2 r1 = __half22float2(acc[1]);
  *reinterpret_cast<float4*>(out + (size_t)pt * 192 + s * 64 + cg * 4) =
      make_float4(r0.x * INV_PLANE_SCALE, r0.y * INV_PLANE_SCALE,
                  r1.x * INV_PLANE_SCALE, r1.y * INV_PLANE_SCALE);
}

// ---------------------------------------------------------------------------
// Fallback: fp32 direct from (C,H,W) if workspace too small.
// ---------------------------------------------------------------------------
__device__ __forceinline__ void sample_acc_chw(const float* __restrict__ plane,
                                               int W, float gx, float gy,
                                               int cg, float4& acc) {
  const float x = (gx + 1.0f) * 0.5f * (float)(W - 1);
  const float y = (gy + 1.0f) * 0.5f * (float)(W - 1);
  const float x0f = floorf(x), y0f = floorf(y);
  float wx[4], wy[4];
  cubic_w(x - x0f, wx);
  cubic_w(y - y0f, wy);
  const int x0 = (int)x0f, y0 = (int)y0f;
  int ix[4], iy[4];
#pragma unroll
  for (int i = 0; i < 4; ++i) {
    int xi = x0 - 1 + i;
    ix[i] = xi < 0 ? 0 : (xi > W - 1 ? W - 1 : xi);
    int yi = y0 - 1 + i;
    iy[i] = yi < 0 ? 0 : (yi > W - 1 ? W - 1 : yi);
  }
  const size_t HW = (size_t)W * W;
  float r[4] = {acc.x, acc.y, acc.z, acc.w};
#pragma unroll
  for (int cc = 0; cc < 4; ++cc) {
    const float* pc = plane + (size_t)(cg * 4 + cc) * HW;
    float a = 0.f;
#pragma unroll
    for (int j = 0; j < 4; ++j) {
      const float* rb = pc + (size_t)iy[j] * W;
      float row = 0.f;
#pragma unroll
      for (int i = 0; i < 4; ++i) row += wx[i] * rb[ix[i]];
      a += wy[j] * row;
    }
    r[cc] += a;
  }
  acc = make_float4(r[0], r[1], r[2], r[3]);
}

__global__ __launch_bounds__(256) void sample_fallback(
    const float* __restrict__ coords, const float* __restrict__ px0,
    const float* __restrict__ py0, const float* __restrict__ pz0,
    const float* __restrict__ px1, const float* __restrict__ py1,
    const float* __restrict__ pz1, const float* __restrict__ px2,
    const float* __restrict__ py2, const float* __restrict__ pz2,
    float* __restrict__ out) {
  const int t = blockIdx.x * 256 + threadIdx.x;
  const int pt = t >> 4;
  const int cg = t & 15;
  if (pt >= NPTS) return;
  const float cx = (coords[pt * 3 + 0] + 1.0f) * 0.5f;
  const float cy = (coords[pt * 3 + 1] + 1.0f) * 0.5f;
  const float cz = (coords[pt * 3 + 2] + 1.0f) * 0.5f;
  const float* xs[3] = {px0, px1, px2};
  const float* ys[3] = {py0, py1, py2};
  const float* zs[3] = {pz0, pz1, pz2};
  const int sw[3] = {256, 128, 64};
  float* optr = out + (size_t)pt * 192 + cg * 4;
#pragma unroll
  for (int s = 0; s < 3; ++s) {
    const int W = sw[s];
    float4 acc = make_float4(0.f, 0.f, 0.f, 0.f);
    sample_acc_chw(xs[s], W, cx, cy, cg, acc);
    sample_acc_chw(ys[s], W, cy, cz, cg, acc);
    sample_acc_chw(zs[s], W, cx, cz, cg, acc);
    *reinterpret_cast<float4*>(optr + s * 64) = acc;
  }
}

// ---------------------------------------------------------------------------
extern "C" void kernel_launch(void* const* d_in, const int* in_sizes, int n_in,
                              void* d_out, int out_size, void* d_ws,
                              size_t ws_size, hipStream_t stream) {
  const float* coords = (const float*)d_in[0];
  const float* px0 = (const float*)d_in[1];
  const float* py0 = (const float*)d_in[2];
  const float* pz0 = (const float*)d_in[3];
  const float* px1 = (const float*)d_in[4];
  const float* py1 = (const float*)d_in[5];
  const float* pz1 = (const float*)d_in[6];
  const float* px2 = (const float*)d_in[7];
  const float* py2 = (const float*)d_in[8];
  const float* pz2 = (const float*)d_in[9];
  float* out = (float*)d_out;

  // ws layout (bytes): f16 planes, counts, cursor, sorted point records
  const size_t TP_BYTES = 33030144;
  const size_t CNT_OFF = TP_BYTES;           // 131072 B
  const size_t CUR_OFF = CNT_OFF + 131072;   // 131072 B
  const size_t PTS_OFF = CUR_OFF + 131072;   // 8,000,000 B
  const size_t NEEDED = PTS_OFF + (size_t)NPTS * 16;

  if (ws_size >= NEEDED) {
    __half* tp = (__half*)d_ws;
    int* counts = (int*)((char*)d_ws + CNT_OFF);
    int* cursor = (int*)((char*)d_ws + CUR_OFF);
    float4* spts = (float4*)((char*)d_ws + PTS_OFF);

    transpose_chw_hwc_f16<<<dim3(65536 / 64, 3), 256, 0, stream>>>(
        px0, py0, pz0, tp + 0, 65536);
    transpose_chw_hwc_f16<<<dim3(16384 / 64, 3), 256, 0, stream>>>(
        px1, py1, pz1, tp + 12582912, 16384);
    transpose_chw_hwc_f16<<<dim3(4096 / 64, 3), 256, 0, stream>>>(
        px2, py2, pz2, tp + 15728640, 4096);

    hipMemsetAsync(counts, 0, NBINS * sizeof(int), stream);
    const int pblocks = (NPTS + 255) / 256;
    bin_count<<<pblocks, 256, 0, stream>>>(coords, counts);
    bin_scan<<<1, 1024, 0, stream>>>(counts, cursor);
    bin_scatter<<<pblocks, 256, 0, stream>>>(coords, cursor, spts);

    const int nwgx = (NPTS * 16) / 256;  // 31250, exact
    sample_sorted16h<<<dim3(nwgx, 3), 256, 0, stream>>>(
        spts, (const ushort*)tp, out, nwgx);
  } else {
    const int sample_blocks = (NPTS * 16 + 255) / 256;
    sample_fallback<<<sample_blocks, 256, 0, stream>>>(
        coords, px0, py0, pz0, px1, py1, pz1, px2, py2, pz2, out);
  }
}

// Round 5
// 416.223 us; speedup vs baseline: 3.3613x; 1.4633x over previous
//
#include <hip/hip_runtime.h>
#include <hip/hip_fp16.h>

#define NPTS 500000
#define NBINS 32768  // 32^3 Morton bins

// Planes stored fp16, pre-scaled by 1024 (exact pow2); final result * 1/1024.
#define PLANE_SCALE 1024.0f
#define INV_PLANE_SCALE 0.0009765625f

// ---------------------------------------------------------------------------
// Keys cubic conv weights, a = -0.75, taps at offsets [-1,0,1,2], t in [0,1)
// ---------------------------------------------------------------------------
__device__ __forceinline__ void cubic_w(float t, float w[4]) {
  const float a = -0.75f;
  const float t1 = t + 1.0f;
  w[0] = ((a * t1 - 5.0f * a) * t1 + 8.0f * a) * t1 - 4.0f * a;
  w[1] = ((a + 2.0f) * t - (a + 3.0f)) * t * t + 1.0f;
  const float u = 1.0f - t;
  w[2] = ((a + 2.0f) * u - (a + 3.0f)) * u * u + 1.0f;
  const float t2 = 2.0f - t;
  w[3] = ((a * t2 - 5.0f * a) * t2 + 8.0f * a) * t2 - 4.0f * a;
}

// ---------------------------------------------------------------------------
// Transpose (C,H,W) fp32 -> (H*W, C) fp16*1024, 3 planes batched on blockIdx.y
// ---------------------------------------------------------------------------
__global__ __launch_bounds__(256) void transpose_chw_hwc_f16(
    const float* __restrict__ p0, const float* __restrict__ p1,
    const float* __restrict__ p2, __half* __restrict__ dst, int HW) {
  __shared__ float lds[64][65];
  const float* src = (blockIdx.y == 0) ? p0 : ((blockIdx.y == 1) ? p1 : p2);
  __half* out = dst + (size_t)blockIdx.y * (size_t)HW * 64;
  const int pixBase = blockIdx.x * 64;
  const int tid = threadIdx.x;
  const int lane = tid & 63;
  const int quad = tid >> 6;
#pragma unroll
  for (int k = 0; k < 16; ++k) {
    const int c = k * 4 + quad;
    lds[c][lane] = src[(size_t)c * HW + pixBase + lane];
  }
  __syncthreads();
#pragma unroll
  for (int k = 0; k < 16; ++k) {
    const int pp = k * 4 + quad;
    out[(size_t)(pixBase + pp) * 64 + lane] =
        __float2half(lds[lane][pp] * PLANE_SCALE);
  }
}

// ---------------------------------------------------------------------------
// Morton binning: count -> scan -> scatter (scatter also pre-gathers coords)
// ---------------------------------------------------------------------------
__device__ __forceinline__ unsigned spread3(unsigned v) {
  return (v & 1u) | ((v & 2u) << 2) | ((v & 4u) << 4) | ((v & 8u) << 6) |
         ((v & 16u) << 8);
}

__device__ __forceinline__ unsigned compact3(unsigned v) {
  // inverse of spread3: gather bits 0,3,6,9,12
  return (v & 1u) | ((v >> 2) & 2u) | ((v >> 4) & 4u) | ((v >> 6) & 8u) |
         ((v >> 8) & 16u);
}

__device__ __forceinline__ int bin_of(float cx, float cy, float cz) {
  int xq = (int)((cx + 1.0f) * 16.0f);
  int yq = (int)((cy + 1.0f) * 16.0f);
  int zq = (int)((cz + 1.0f) * 16.0f);
  xq = xq < 0 ? 0 : (xq > 31 ? 31 : xq);
  yq = yq < 0 ? 0 : (yq > 31 ? 31 : yq);
  zq = zq < 0 ? 0 : (zq > 31 ? 31 : zq);
  return (int)(spread3((unsigned)xq) | (spread3((unsigned)yq) << 1) |
               (spread3((unsigned)zq) << 2));
}

__global__ __launch_bounds__(256) void bin_count(
    const float* __restrict__ coords, int* __restrict__ counts) {
  const int pt = blockIdx.x * 256 + threadIdx.x;
  if (pt >= NPTS) return;
  const int b = bin_of(coords[pt * 3], coords[pt * 3 + 1], coords[pt * 3 + 2]);
  atomicAdd(&counts[b], 1);
}

__global__ __launch_bounds__(1024) void bin_scan(
    const int* __restrict__ counts, int* __restrict__ cursor) {
  __shared__ int lds[1024];
  const int t = threadIdx.x;
  const int base = t * 32;
  int s = 0;
#pragma unroll
  for (int i = 0; i < 32; ++i) s += counts[base + i];
  lds[t] = s;
  __syncthreads();
  int own = s;
  for (int off = 1; off < 1024; off <<= 1) {
    int v = (t >= off) ? lds[t - off] : 0;
    __syncthreads();
    lds[t] += v;
    __syncthreads();
  }
  int run = lds[t] - own;
#pragma unroll
  for (int i = 0; i < 32; ++i) {
    cursor[base + i] = run;
    run += counts[base + i];
  }
}

__global__ __launch_bounds__(256) void bin_scatter(
    const float* __restrict__ coords, int* __restrict__ cursor,
    float4* __restrict__ spts) {
  const int pt = blockIdx.x * 256 + threadIdx.x;
  if (pt >= NPTS) return;
  const float x = coords[pt * 3], y = coords[pt * 3 + 1], z = coords[pt * 3 + 2];
  const int b = bin_of(x, y, z);
  const int pos = atomicAdd(&cursor[b], 1);
  spts[pos] = make_float4(x, y, z, __int_as_float(pt));
}

// ---------------------------------------------------------------------------
// Per-bin LDS-staged sampling. One block per (bin, scale).
// LDS: 3 planes x 8 rows x 8 cols x 64ch fp16 = 3 x 1024 uint2 = 24 KB.
// ---------------------------------------------------------------------------
__global__ __launch_bounds__(256, 4) void sample_bins(
    const float4* __restrict__ spts, const ushort* __restrict__ tp,
    const int* __restrict__ counts, const int* __restrict__ endc,
    float* __restrict__ out) {
  __shared__ uint2 win[3072];

  // bijective XCD swizzle over 32768 bins (divisible by 8)
  const int orig = blockIdx.x;
  const int b = (orig & 7) * (NBINS / 8) + (orig >> 3);

  const int end = endc[b];
  const int cnt = counts[b];
  const int start = end - cnt;
  if (cnt == 0) return;

  const int s = blockIdx.y;
  const int W = (s == 0) ? 256 : ((s == 1) ? 128 : 64);
  const size_t sbase = (s == 0) ? 0 : ((s == 1) ? 12582912 : 15728640);
  const size_t psz = (size_t)W * W * 64;  // ushorts per plane

  // bin coords and per-axis window bases
  const int qx = (int)compact3((unsigned)b);
  const int qy = (int)compact3((unsigned)b >> 1);
  const int qz = (int)compact3((unsigned)b >> 2);
  const float hw = 0.5f * (float)(W - 1);
  const float fbx = floorf((1.0f + (float)qx * 0.03125f) * hw);
  const float fby = floorf((1.0f + (float)qy * 0.03125f) * hw);
  const float fbz = floorf((1.0f + (float)qz * 0.03125f) * hw);
  const int wbx = (int)fbx - 1;  // window col/row start per axis
  const int wby = (int)fby - 1;
  const int wbz = (int)fbz - 1;

  // ---- stage 3 windows: planes p0=xy(col=x,row=y) p1=yz(col=y,row=z)
  //                              p2=xz(col=x,row=z)
  const char* tpb = (const char*)(tp + sbase);
  const int tid = threadIdx.x;
#pragma unroll
  for (int k = 0; k < 12; ++k) {
    const int chunk = tid + k * 256;
    const int p = chunk >> 10;
    const int q = chunk & 1023;
    const int row = q >> 7;
    const int col = (q >> 4) & 7;
    const int c16 = q & 15;
    const int rbase = (p == 0) ? wby : wbz;
    const int cbase = (p == 1) ? wby : wbx;
    int gr = rbase + row;
    gr = gr < 0 ? 0 : (gr > W - 1 ? W - 1 : gr);
    int gc = cbase + col;
    gc = gc < 0 ? 0 : (gc > W - 1 ? W - 1 : gc);
    const char* src =
        tpb + (size_t)p * psz * 2 + ((size_t)gr * W + gc) * 128 + c16 * 8;
    win[chunk] = *reinterpret_cast<const uint2*>(src);
  }
  __syncthreads();

  // ---- per-point sampling from LDS
  const int lanegrp = tid >> 4;  // 16 points per 256-thr chunk
  const int cg = tid & 15;       // 4 channels per lane

  for (int i0 = start; i0 < end; i0 += 16) {
    const int slot = i0 + lanegrp;
    if (slot >= end) break;  // no further syncs; divergence is fine
    const float4 P = spts[slot];
    const int pt = __float_as_int(P.w);

    // per-axis taps: window-relative offsets + fp16 broadcast weights
    int xc16[4], yc16[4], yr128[4], zr128[4];
    __half2 wx2[4], wy2[4], wz2[4];
    {
      const float c = (P.x + 1.0f) * 0.5f;
      const float x = (c + 1.0f) * 0.5f * (float)(W - 1);
      const float x0f = floorf(x);
      float w[4];
      cubic_w(x - x0f, w);
      const int rel = (int)x0f - (wbx + 1);  // x0 - floor(fbx)
#pragma unroll
      for (int i = 0; i < 4; ++i) {
        int wi = rel + i;
        wi = wi < 0 ? 0 : (wi > 7 ? 7 : wi);
        xc16[i] = wi * 16;
        wx2[i] = __half2half2(__float2half(w[i]));
      }
    }
    {
      const float c = (P.y + 1.0f) * 0.5f;
      const float x = (c + 1.0f) * 0.5f * (float)(W - 1);
      const float x0f = floorf(x);
      float w[4];
      cubic_w(x - x0f, w);
      const int rel = (int)x0f - (wby + 1);
#pragma unroll
      for (int i = 0; i < 4; ++i) {
        int wi = rel + i;
        wi = wi < 0 ? 0 : (wi > 7 ? 7 : wi);
        yc16[i] = wi * 16;
        yr128[i] = wi * 128;
        wy2[i] = __half2half2(__float2half(w[i]));
      }
    }
    {
      const float c = (P.z + 1.0f) * 0.5f;
      const float x = (c + 1.0f) * 0.5f * (float)(W - 1);
      const float x0f = floorf(x);
      float w[4];
      cubic_w(x - x0f, w);
      const int rel = (int)x0f - (wbz + 1);
#pragma unroll
      for (int i = 0; i < 4; ++i) {
        int wi = rel + i;
        wi = wi < 0 ? 0 : (wi > 7 ? 7 : wi);
        zr128[i] = wi * 128;
        wz2[i] = __half2half2(__float2half(w[i]));
      }
    }

    __half2 acc0 = __float2half2_rn(0.0f);
    __half2 acc1 = __float2half2_rn(0.0f);

#define SAMP(PBASE, C16, CW, R128, RW)                                   \
  _Pragma("unroll") for (int j = 0; j < 4; ++j) {                        \
    const int rb = (PBASE) + R128[j] + cg;                               \
    __half2 r0 = __float2half2_rn(0.0f);                                 \
    __half2 r1 = __float2half2_rn(0.0f);                                 \
    _Pragma("unroll") for (int i = 0; i < 4; ++i) {                      \
      const uint2 v = win[rb + C16[i]];                                  \
      r0 = __hfma2(CW[i], *reinterpret_cast<const __half2*>(&v.x), r0);  \
      r1 = __hfma2(CW[i], *reinterpret_cast<const __half2*>(&v.y), r1);  \
    }                                                                    \
    acc0 = __hfma2(RW[j], r0, acc0);                                     \
    acc1 = __hfma2(RW[j], r1, acc1);                                     \
  }

    SAMP(0, xc16, wx2, yr128, wy2);     // xy: col=x, row=y
    SAMP(1024, yc16, wy2, zr128, wz2);  // yz: col=y, row=z
    SAMP(2048, xc16, wx2, zr128, wz2);  // xz: col=x, row=z
#undef SAMP

    const float2 r0 = __half22float2(acc0);
    const float2 r1 = __half22float2(acc1);
    *reinterpret_cast<float4*>(out + (size_t)pt * 192 + s * 64 + cg * 4) =
        make_float4(r0.x * INV_PLANE_SCALE, r0.y * INV_PLANE_SCALE,
                    r1.x * INV_PLANE_SCALE, r1.y * INV_PLANE_SCALE);
  }
}

// ---------------------------------------------------------------------------
// Fallback: fp32 direct from (C,H,W) if workspace too small.
// ---------------------------------------------------------------------------
__device__ __forceinline__ void sample_acc_chw(const float* __restrict__ plane,
                                               int W, float gx, float gy,
                                               int cg, float4& acc) {
  const float x = (gx + 1.0f) * 0.5f * (float)(W - 1);
  const float y = (gy + 1.0f) * 0.5f * (float)(W - 1);
  const float x0f = floorf(x), y0f = floorf(y);
  float wx[4], wy[4];
  cubic_w(x - x0f, wx);
  cubic_w(y - y0f, wy);
  const int x0 = (int)x0f, y0 = (int)y0f;
  int ix[4], iy[4];
#pragma unroll
  for (int i = 0; i < 4; ++i) {
    int xi = x0 - 1 + i;
    ix[i] = xi < 0 ? 0 : (xi > W - 1 ? W - 1 : xi);
    int yi = y0 - 1 + i;
    iy[i] = yi < 0 ? 0 : (yi > W - 1 ? W - 1 : yi);
  }
  const size_t HW = (size_t)W * W;
  float r[4] = {acc.x, acc.y, acc.z, acc.w};
#pragma unroll
  for (int cc = 0; cc < 4; ++cc) {
    const float* pc = plane + (size_t)(cg * 4 + cc) * HW;
    float a = 0.f;
#pragma unroll
    for (int j = 0; j < 4; ++j) {
      const float* rb = pc + (size_t)iy[j] * W;
      float row = 0.f;
#pragma unroll
      for (int i = 0; i < 4; ++i) row += wx[i] * rb[ix[i]];
      a += wy[j] * row;
    }
    r[cc] += a;
  }
  acc = make_float4(r[0], r[1], r[2], r[3]);
}

__global__ __launch_bounds__(256) void sample_fallback(
    const float* __restrict__ coords, const float* __restrict__ px0,
    const float* __restrict__ py0, const float* __restrict__ pz0,
    const float* __restrict__ px1, const float* __restrict__ py1,
    const float* __restrict__ pz1, const float* __restrict__ px2,
    const float* __restrict__ py2, const float* __restrict__ pz2,
    float* __restrict__ out) {
  const int t = blockIdx.x * 256 + threadIdx.x;
  const int pt = t >> 4;
  const int cg = t & 15;
  if (pt >= NPTS) return;
  const float cx = (coords[pt * 3 + 0] + 1.0f) * 0.5f;
  const float cy = (coords[pt * 3 + 1] + 1.0f) * 0.5f;
  const float cz = (coords[pt * 3 + 2] + 1.0f) * 0.5f;
  const float* xs[3] = {px0, px1, px2};
  const float* ys[3] = {py0, py1, py2};
  const float* zs[3] = {pz0, pz1, pz2};
  const int sw[3] = {256, 128, 64};
  float* optr = out + (size_t)pt * 192 + cg * 4;
#pragma unroll
  for (int s = 0; s < 3; ++s) {
    const int W = sw[s];
    float4 acc = make_float4(0.f, 0.f, 0.f, 0.f);
    sample_acc_chw(xs[s], W, cx, cy, cg, acc);
    sample_acc_chw(ys[s], W, cy, cz, cg, acc);
    sample_acc_chw(zs[s], W, cx, cz, cg, acc);
    *reinterpret_cast<float4*>(optr + s * 64) = acc;
  }
}

// ---------------------------------------------------------------------------
extern "C" void kernel_launch(void* const* d_in, const int* in_sizes, int n_in,
                              void* d_out, int out_size, void* d_ws,
                              size_t ws_size, hipStream_t stream) {
  const float* coords = (const float*)d_in[0];
  const float* px0 = (const float*)d_in[1];
  const float* py0 = (const float*)d_in[2];
  const float* pz0 = (const float*)d_in[3];
  const float* px1 = (const float*)d_in[4];
  const float* py1 = (const float*)d_in[5];
  const float* pz1 = (const float*)d_in[6];
  const float* px2 = (const float*)d_in[7];
  const float* py2 = (const float*)d_in[8];
  const float* pz2 = (const float*)d_in[9];
  float* out = (float*)d_out;

  // ws layout (bytes): f16 planes, counts, end-cursor, sorted point records
  const size_t TP_BYTES = 33030144;
  const size_t CNT_OFF = TP_BYTES;           // 131072 B
  const size_t CUR_OFF = CNT_OFF + 131072;   // 131072 B
  const size_t PTS_OFF = CUR_OFF + 131072;   // 8,000,000 B
  const size_t NEEDED = PTS_OFF + (size_t)NPTS * 16;

  if (ws_size >= NEEDED) {
    __half* tp = (__half*)d_ws;
    int* counts = (int*)((char*)d_ws + CNT_OFF);
    int* cursor = (int*)((char*)d_ws + CUR_OFF);
    float4* spts = (float4*)((char*)d_ws + PTS_OFF);

    transpose_chw_hwc_f16<<<dim3(65536 / 64, 3), 256, 0, stream>>>(
        px0, py0, pz0, tp + 0, 65536);
    transpose_chw_hwc_f16<<<dim3(16384 / 64, 3), 256, 0, stream>>>(
        px1, py1, pz1, tp + 12582912, 16384);
    transpose_chw_hwc_f16<<<dim3(4096 / 64, 3), 256, 0, stream>>>(
        px2, py2, pz2, tp + 15728640, 4096);

    hipMemsetAsync(counts, 0, NBINS * sizeof(int), stream);
    const int pblocks = (NPTS + 255) / 256;
    bin_count<<<pblocks, 256, 0, stream>>>(coords, counts);
    bin_scan<<<1, 1024, 0, stream>>>(counts, cursor);
    bin_scatter<<<pblocks, 256, 0, stream>>>(coords, cursor, spts);
    // cursor[b] now == end offset of bin b

    sample_bins<<<dim3(NBINS, 3), 256, 0, stream>>>(
        spts, (const ushort*)tp, counts, cursor, out);
  } else {
    const int sample_blocks = (NPTS * 16 + 255) / 256;
    sample_fallback<<<sample_blocks, 256, 0, stream>>>(
        coords, px0, py0, pz0, px1, py1, pz1, px2, py2, pz2, out);
  }
}

// Round 6
// 386.634 us; speedup vs baseline: 3.6185x; 1.0765x over previous
//
#include <hip/hip_runtime.h>
#include <hip/hip_fp16.h>

#define NPTS 500000
#define NBINS 32768   // 32^3 Morton bins
#define NSUPER 16384  // bins merged in pairs along x

// Planes stored fp16, pre-scaled by 1024 (exact pow2); final result * 1/1024.
#define PLANE_SCALE 1024.0f
#define INV_PLANE_SCALE 0.0009765625f

// ---------------------------------------------------------------------------
// Keys cubic conv weights, a = -0.75, taps at offsets [-1,0,1,2], t in [0,1)
// ---------------------------------------------------------------------------
__device__ __forceinline__ void cubic_w(float t, float w[4]) {
  const float a = -0.75f;
  const float t1 = t + 1.0f;
  w[0] = ((a * t1 - 5.0f * a) * t1 + 8.0f * a) * t1 - 4.0f * a;
  w[1] = ((a + 2.0f) * t - (a + 3.0f)) * t * t + 1.0f;
  const float u = 1.0f - t;
  w[2] = ((a + 2.0f) * u - (a + 3.0f)) * u * u + 1.0f;
  const float t2 = 2.0f - t;
  w[3] = ((a * t2 - 5.0f * a) * t2 + 8.0f * a) * t2 - 4.0f * a;
}

// ---------------------------------------------------------------------------
// Transpose (C,H,W) fp32 -> (H*W, C) fp16*1024, 3 planes batched on blockIdx.y
// ---------------------------------------------------------------------------
__global__ __launch_bounds__(256) void transpose_chw_hwc_f16(
    const float* __restrict__ p0, const float* __restrict__ p1,
    const float* __restrict__ p2, __half* __restrict__ dst, int HW) {
  __shared__ float lds[64][65];
  const float* src = (blockIdx.y == 0) ? p0 : ((blockIdx.y == 1) ? p1 : p2);
  __half* out = dst + (size_t)blockIdx.y * (size_t)HW * 64;
  const int pixBase = blockIdx.x * 64;
  const int tid = threadIdx.x;
  const int lane = tid & 63;
  const int quad = tid >> 6;
#pragma unroll
  for (int k = 0; k < 16; ++k) {
    const int c = k * 4 + quad;
    lds[c][lane] = src[(size_t)c * HW + pixBase + lane];
  }
  __syncthreads();
#pragma unroll
  for (int k = 0; k < 16; ++k) {
    const int pp = k * 4 + quad;
    out[(size_t)(pixBase + pp) * 64 + lane] =
        __float2half(lds[lane][pp] * PLANE_SCALE);
  }
}

// ---------------------------------------------------------------------------
// Morton binning: count -> scan -> scatter (scatter also pre-gathers coords)
// ---------------------------------------------------------------------------
__device__ __forceinline__ unsigned spread3(unsigned v) {
  return (v & 1u) | ((v & 2u) << 2) | ((v & 4u) << 4) | ((v & 8u) << 6) |
         ((v & 16u) << 8);
}

__device__ __forceinline__ unsigned compact3(unsigned v) {
  return (v & 1u) | ((v >> 2) & 2u) | ((v >> 4) & 4u) | ((v >> 6) & 8u) |
         ((v >> 8) & 16u);
}

__device__ __forceinline__ int bin_of(float cx, float cy, float cz) {
  int xq = (int)((cx + 1.0f) * 16.0f);
  int yq = (int)((cy + 1.0f) * 16.0f);
  int zq = (int)((cz + 1.0f) * 16.0f);
  xq = xq < 0 ? 0 : (xq > 31 ? 31 : xq);
  yq = yq < 0 ? 0 : (yq > 31 ? 31 : yq);
  zq = zq < 0 ? 0 : (zq > 31 ? 31 : zq);
  return (int)(spread3((unsigned)xq) | (spread3((unsigned)yq) << 1) |
               (spread3((unsigned)zq) << 2));
}

__global__ __launch_bounds__(256) void bin_count(
    const float* __restrict__ coords, int* __restrict__ counts) {
  const int pt = blockIdx.x * 256 + threadIdx.x;
  if (pt >= NPTS) return;
  const int b = bin_of(coords[pt * 3], coords[pt * 3 + 1], coords[pt * 3 + 2]);
  atomicAdd(&counts[b], 1);
}

__global__ __launch_bounds__(1024) void bin_scan(
    const int* __restrict__ counts, int* __restrict__ cursor) {
  __shared__ int lds[1024];
  const int t = threadIdx.x;
  const int base = t * 32;
  int s = 0;
#pragma unroll
  for (int i = 0; i < 32; ++i) s += counts[base + i];
  lds[t] = s;
  __syncthreads();
  int own = s;
  for (int off = 1; off < 1024; off <<= 1) {
    int v = (t >= off) ? lds[t - off] : 0;
    __syncthreads();
    lds[t] += v;
    __syncthreads();
  }
  int run = lds[t] - own;
#pragma unroll
  for (int i = 0; i < 32; ++i) {
    cursor[base + i] = run;
    run += counts[base + i];
  }
}

__global__ __launch_bounds__(256) void bin_scatter(
    const float* __restrict__ coords, int* __restrict__ cursor,
    float4* __restrict__ spts) {
  const int pt = blockIdx.x * 256 + threadIdx.x;
  if (pt >= NPTS) return;
  const float x = coords[pt * 3], y = coords[pt * 3 + 1], z = coords[pt * 3 + 2];
  const int b = bin_of(x, y, z);
  const int pos = atomicAdd(&cursor[b], 1);
  spts[pos] = make_float4(x, y, z, __int_as_float(pt));
}

// ---------------------------------------------------------------------------
// Weight precompute: one thread per (sorted slot, scale). 32-B record:
// {wx01, wx23, wy01, wy23, wz01, wz23, relx|rely<<8|relz<<16, pt}
// rel are window-relative tap bases for the x-merged superbin window.
// ---------------------------------------------------------------------------
__global__ __launch_bounds__(256) void prep_weights(
    const float4* __restrict__ spts, uint4* __restrict__ wrec) {
  const int slot = blockIdx.x * 256 + threadIdx.x;
  if (slot >= NPTS) return;
  const int s = blockIdx.y;
  const float4 P = spts[slot];
  const int W = (s == 0) ? 256 : ((s == 1) ? 128 : 64);
  const float hw = 0.5f * (float)(W - 1);

  const int b = bin_of(P.x, P.y, P.z);
  const int qx0 = ((int)compact3((unsigned)b)) & ~1;
  const int qy = (int)compact3((unsigned)b >> 1);
  const int qz = (int)compact3((unsigned)b >> 2);
  const int fb[3] = {(int)floorf((1.0f + (float)qx0 * 0.03125f) * hw),
                     (int)floorf((1.0f + (float)qy * 0.03125f) * hw),
                     (int)floorf((1.0f + (float)qz * 0.03125f) * hw)};
  const float vin[3] = {P.x, P.y, P.z};

  uint wp[6];
  int rel[3];
#pragma unroll
  for (int a = 0; a < 3; ++a) {
    const float c = (vin[a] + 1.0f) * 0.5f;
    const float x = (c + 1.0f) * 0.5f * (float)(W - 1);
    const float x0f = floorf(x);
    float w[4];
    cubic_w(x - x0f, w);
    int r = (int)x0f - fb[a];
    const int rmax = (a == 0) ? 12 : 4;
    r = r < 0 ? 0 : (r > rmax ? rmax : r);
    rel[a] = r;
    const __half2 lo = __halves2half2(__float2half(w[0]), __float2half(w[1]));
    const __half2 hi = __halves2half2(__float2half(w[2]), __float2half(w[3]));
    wp[a * 2] = *(const uint*)&lo;
    wp[a * 2 + 1] = *(const uint*)&hi;
  }
  uint4* dst = wrec + ((size_t)s * NPTS + slot) * 2;
  dst[0] = make_uint4(wp[0], wp[1], wp[2], wp[3]);
  dst[1] = make_uint4(
      wp[4], wp[5],
      (uint)rel[0] | ((uint)rel[1] << 8) | ((uint)rel[2] << 16),
      (uint)__float_as_uint(P.w));
}

// ---------------------------------------------------------------------------
// Superbin sampling: one block per (superbin, scale). LDS windows:
// XY 8y x 16x, YZ 8z x 8y, XZ 8z x 16x; 8 ch-groups of uint4 -> 40 KB.
// XOR bank swizzle: cg' = cg ^ (row & 7).
// ---------------------------------------------------------------------------
__global__ __launch_bounds__(256, 4) void sample_super(
    const uint4* __restrict__ wrec, const ushort* __restrict__ tp,
    const int* __restrict__ counts, const int* __restrict__ endc,
    float* __restrict__ out) {
  __shared__ uint4 win[2560];

  const int orig = blockIdx.x;
  const int sb = (orig & 7) * (NSUPER / 8) + (orig >> 3);
  const int b0 = sb * 2;
  const int start = endc[b0] - counts[b0];
  const int end = endc[b0 + 1];
  if (start >= end) return;

  const int s = blockIdx.y;
  const int W = (s == 0) ? 256 : ((s == 1) ? 128 : 64);
  const size_t sbase = (s == 0) ? 0 : ((s == 1) ? 12582912 : 15728640);
  const size_t psz = (size_t)W * W * 64;
  const float hw = 0.5f * (float)(W - 1);

  const int qx0 = ((int)compact3((unsigned)b0)) & ~1;
  const int qy = (int)compact3((unsigned)b0 >> 1);
  const int qz = (int)compact3((unsigned)b0 >> 2);
  const int wbx = (int)floorf((1.0f + (float)qx0 * 0.03125f) * hw) - 1;
  const int wby = (int)floorf((1.0f + (float)qy * 0.03125f) * hw) - 1;
  const int wbz = (int)floorf((1.0f + (float)qz * 0.03125f) * hw) - 1;

  const char* tpb = (const char*)(tp + sbase);
  const int tid = threadIdx.x;
#pragma unroll
  for (int k = 0; k < 10; ++k) {
    const int chunk = tid + k * 256;
    int row, col, cg, grow, gcol, p;
    if (chunk < 1024) {  // XY: row=y, col=x (16 wide)
      p = 0;
      row = chunk >> 7;
      col = (chunk >> 3) & 15;
      cg = chunk & 7;
      grow = wby + row;
      gcol = wbx + col;
    } else if (chunk < 1536) {  // YZ: row=z, col=y (8 wide)
      const int q = chunk - 1024;
      p = 1;
      row = q >> 6;
      col = (q >> 3) & 7;
      cg = q & 7;
      grow = wbz + row;
      gcol = wby + col;
    } else {  // XZ: row=z, col=x (16 wide)
      const int q = chunk - 1536;
      p = 2;
      row = q >> 7;
      col = (q >> 3) & 15;
      cg = q & 7;
      grow = wbz + row;
      gcol = wbx + col;
    }
    grow = grow < 0 ? 0 : (grow > W - 1 ? W - 1 : grow);
    gcol = gcol < 0 ? 0 : (gcol > W - 1 ? W - 1 : gcol);
    const char* src =
        tpb + (size_t)p * psz * 2 + ((size_t)grow * W + gcol) * 128 + cg * 16;
    win[(chunk & ~7) | (cg ^ (row & 7))] = *reinterpret_cast<const uint4*>(src);
  }
  __syncthreads();

  const int lanegrp = tid >> 3;  // 32 point slots per iteration
  const int cg = tid & 7;        // 8 channels per lane

  for (int i0 = start; i0 < end; i0 += 32) {
    const int slot = i0 + lanegrp;
    if (slot >= end) break;
    const uint4 r0 = wrec[((size_t)s * NPTS + slot) * 2];
    const uint4 r1 = wrec[((size_t)s * NPTS + slot) * 2 + 1];
    const int pt = (int)r1.w;
    const int relx = (int)(r1.z & 255u);
    const int rely = (int)((r1.z >> 8) & 255u);
    const int relz = (int)((r1.z >> 16) & 255u);

    __half2 wx[4], wy[4], wz[4];
    {
      const __half2 hx01 = *(const __half2*)&r0.x;
      const __half2 hx23 = *(const __half2*)&r0.y;
      const __half2 hy01 = *(const __half2*)&r0.z;
      const __half2 hy23 = *(const __half2*)&r0.w;
      const __half2 hz01 = *(const __half2*)&r1.x;
      const __half2 hz23 = *(const __half2*)&r1.y;
      wx[0] = __half2half2(__low2half(hx01));
      wx[1] = __half2half2(__high2half(hx01));
      wx[2] = __half2half2(__low2half(hx23));
      wx[3] = __half2half2(__high2half(hx23));
      wy[0] = __half2half2(__low2half(hy01));
      wy[1] = __half2half2(__high2half(hy01));
      wy[2] = __half2half2(__low2half(hy23));
      wy[3] = __half2half2(__high2half(hy23));
      wz[0] = __half2half2(__low2half(hz01));
      wz[1] = __half2half2(__high2half(hz01));
      wz[2] = __half2half2(__low2half(hz23));
      wz[3] = __half2half2(__high2half(hz23));
    }

    int xo[4], yo[4], zo[4];
#pragma unroll
    for (int i = 0; i < 4; ++i) {
      int xi = relx + i;
      xo[i] = (xi > 15 ? 15 : xi) * 8;
      int yi = rely + i;
      yo[i] = yi > 7 ? 7 : yi;
      int zi = relz + i;
      zo[i] = zi > 7 ? 7 : zi;
    }

    __half2 a0 = __float2half2_rn(0.0f), a1 = a0, a2 = a0, a3 = a0;

#define TAPS(RB, CO, CW, RW_j)                                        \
  {                                                                   \
    __half2 q0 = __float2half2_rn(0.0f), q1 = q0, q2 = q0, q3 = q0;   \
    _Pragma("unroll") for (int i = 0; i < 4; ++i) {                   \
      const uint4 v = win[(RB) + CO[i]];                              \
      q0 = __hfma2(CW[i], *(const __half2*)&v.x, q0);                 \
      q1 = __hfma2(CW[i], *(const __half2*)&v.y, q1);                 \
      q2 = __hfma2(CW[i], *(const __half2*)&v.z, q2);                 \
      q3 = __hfma2(CW[i], *(const __half2*)&v.w, q3);                 \
    }                                                                 \
    a0 = __hfma2(RW_j, q0, a0);                                       \
    a1 = __hfma2(RW_j, q1, a1);                                       \
    a2 = __hfma2(RW_j, q2, a2);                                       \
    a3 = __hfma2(RW_j, q3, a3);                                       \
  }

#pragma unroll
    for (int j = 0; j < 4; ++j)  // XY: row=y, col=x
      TAPS(yo[j] * 128 + (cg ^ yo[j]), xo, wx, wy[j]);
#pragma unroll
    for (int j = 0; j < 4; ++j) {  // YZ: row=z, col=y
      const int rb = 1024 + zo[j] * 64 + (cg ^ zo[j]);
      __half2 q0 = __float2half2_rn(0.0f), q1 = q0, q2 = q0, q3 = q0;
#pragma unroll
      for (int i = 0; i < 4; ++i) {
        const uint4 v = win[rb + yo[i] * 8];
        q0 = __hfma2(wy[i], *(const __half2*)&v.x, q0);
        q1 = __hfma2(wy[i], *(const __half2*)&v.y, q1);
        q2 = __hfma2(wy[i], *(const __half2*)&v.z, q2);
        q3 = __hfma2(wy[i], *(const __half2*)&v.w, q3);
      }
      a0 = __hfma2(wz[j], q0, a0);
      a1 = __hfma2(wz[j], q1, a1);
      a2 = __hfma2(wz[j], q2, a2);
      a3 = __hfma2(wz[j], q3, a3);
    }
#pragma unroll
    for (int j = 0; j < 4; ++j)  // XZ: row=z, col=x
      TAPS(1536 + zo[j] * 128 + (cg ^ zo[j]), xo, wx, wz[j]);
#undef TAPS

    const float2 f0 = __half22float2(a0);
    const float2 f1 = __half22float2(a1);
    const float2 f2 = __half22float2(a2);
    const float2 f3 = __half22float2(a3);
    float* optr = out + (size_t)pt * 192 + s * 64 + cg * 8;
    *reinterpret_cast<float4*>(optr) =
        make_float4(f0.x * INV_PLANE_SCALE, f0.y * INV_PLANE_SCALE,
                    f1.x * INV_PLANE_SCALE, f1.y * INV_PLANE_SCALE);
    *reinterpret_cast<float4*>(optr + 4) =
        make_float4(f2.x * INV_PLANE_SCALE, f2.y * INV_PLANE_SCALE,
                    f3.x * INV_PLANE_SCALE, f3.y * INV_PLANE_SCALE);
  }
}

// ---------------------------------------------------------------------------
// Fallback: fp32 direct from (C,H,W) if workspace too small.
// ---------------------------------------------------------------------------
__device__ __forceinline__ void sample_acc_chw(const float* __restrict__ plane,
                                               int W, float gx, float gy,
                                               int cg, float4& acc) {
  const float x = (gx + 1.0f) * 0.5f * (float)(W - 1);
  const float y = (gy + 1.0f) * 0.5f * (float)(W - 1);
  const float x0f = floorf(x), y0f = floorf(y);
  float wx[4], wy[4];
  cubic_w(x - x0f, wx);
  cubic_w(y - y0f, wy);
  const int x0 = (int)x0f, y0 = (int)y0f;
  int ix[4], iy[4];
#pragma unroll
  for (int i = 0; i < 4; ++i) {
    int xi = x0 - 1 + i;
    ix[i] = xi < 0 ? 0 : (xi > W - 1 ? W - 1 : xi);
    int yi = y0 - 1 + i;
    iy[i] = yi < 0 ? 0 : (yi > W - 1 ? W - 1 : yi);
  }
  const size_t HW = (size_t)W * W;
  float r[4] = {acc.x, acc.y, acc.z, acc.w};
#pragma unroll
  for (int cc = 0; cc < 4; ++cc) {
    const float* pc = plane + (size_t)(cg * 4 + cc) * HW;
    float a = 0.f;
#pragma unroll
    for (int j = 0; j < 4; ++j) {
      const float* rb = pc + (size_t)iy[j] * W;
      float row = 0.f;
#pragma unroll
      for (int i = 0; i < 4; ++i) row += wx[i] * rb[ix[i]];
      a += wy[j] * row;
    }
    r[cc] += a;
  }
  acc = make_float4(r[0], r[1], r[2], r[3]);
}

__global__ __launch_bounds__(256) void sample_fallback(
    const float* __restrict__ coords, const float* __restrict__ px0,
    const float* __restrict__ py0, const float* __restrict__ pz0,
    const float* __restrict__ px1, const float* __restrict__ py1,
    const float* __restrict__ pz1, const float* __restrict__ px2,
    const float* __restrict__ py2, const float* __restrict__ pz2,
    float* __restrict__ out) {
  const int t = blockIdx.x * 256 + threadIdx.x;
  const int pt = t >> 4;
  const int cg = t & 15;
  if (pt >= NPTS) return;
  const float cx = (coords[pt * 3 + 0] + 1.0f) * 0.5f;
  const float cy = (coords[pt * 3 + 1] + 1.0f) * 0.5f;
  const float cz = (coords[pt * 3 + 2] + 1.0f) * 0.5f;
  const float* xs[3] = {px0, px1, px2};
  const float* ys[3] = {py0, py1, py2};
  const float* zs[3] = {pz0, pz1, pz2};
  const int sw[3] = {256, 128, 64};
  float* optr = out + (size_t)pt * 192 + cg * 4;
#pragma unroll
  for (int s = 0; s < 3; ++s) {
    const int W = sw[s];
    float4 acc = make_float4(0.f, 0.f, 0.f, 0.f);
    sample_acc_chw(xs[s], W, cx, cy, cg, acc);
    sample_acc_chw(ys[s], W, cy, cz, cg, acc);
    sample_acc_chw(zs[s], W, cx, cz, cg, acc);
    *reinterpret_cast<float4*>(optr + s * 64) = acc;
  }
}

// ---------------------------------------------------------------------------
extern "C" void kernel_launch(void* const* d_in, const int* in_sizes, int n_in,
                              void* d_out, int out_size, void* d_ws,
                              size_t ws_size, hipStream_t stream) {
  const float* coords = (const float*)d_in[0];
  const float* px0 = (const float*)d_in[1];
  const float* py0 = (const float*)d_in[2];
  const float* pz0 = (const float*)d_in[3];
  const float* px1 = (const float*)d_in[4];
  const float* py1 = (const float*)d_in[5];
  const float* pz1 = (const float*)d_in[6];
  const float* px2 = (const float*)d_in[7];
  const float* py2 = (const float*)d_in[8];
  const float* pz2 = (const float*)d_in[9];
  float* out = (float*)d_out;

  // ws layout (bytes): f16 planes, counts, end-cursor, sorted pts, weight recs
  const size_t TP_BYTES = 33030144;
  const size_t CNT_OFF = TP_BYTES;             // 131072 B
  const size_t CUR_OFF = CNT_OFF + 131072;     // 131072 B
  const size_t PTS_OFF = CUR_OFF + 131072;     // 8,000,000 B
  const size_t REC_OFF = PTS_OFF + (size_t)NPTS * 16;  // 48,000,000 B
  const size_t NEEDED = REC_OFF + (size_t)NPTS * 3 * 32;

  if (ws_size >= NEEDED) {
    __half* tp = (__half*)d_ws;
    int* counts = (int*)((char*)d_ws + CNT_OFF);
    int* cursor = (int*)((char*)d_ws + CUR_OFF);
    float4* spts = (float4*)((char*)d_ws + PTS_OFF);
    uint4* wrec = (uint4*)((char*)d_ws + REC_OFF);

    transpose_chw_hwc_f16<<<dim3(65536 / 64, 3), 256, 0, stream>>>(
        px0, py0, pz0, tp + 0, 65536);
    transpose_chw_hwc_f16<<<dim3(16384 / 64, 3), 256, 0, stream>>>(
        px1, py1, pz1, tp + 12582912, 16384);
    transpose_chw_hwc_f16<<<dim3(4096 / 64, 3), 256, 0, stream>>>(
        px2, py2, pz2, tp + 15728640, 4096);

    hipMemsetAsync(counts, 0, NBINS * sizeof(int), stream);
    const int pblocks = (NPTS + 255) / 256;
    bin_count<<<pblocks, 256, 0, stream>>>(coords, counts);
    bin_scan<<<1, 1024, 0, stream>>>(counts, cursor);
    bin_scatter<<<pblocks, 256, 0, stream>>>(coords, cursor, spts);
    // cursor[b] now == end offset of bin b

    prep_weights<<<dim3(pblocks, 3), 256, 0, stream>>>(spts, wrec);

    sample_super<<<dim3(NSUPER, 3), 256, 0, stream>>>(
        wrec, (const ushort*)tp, counts, cursor, out);
  } else {
    const int sample_blocks = (NPTS * 16 + 255) / 256;
    sample_fallback<<<sample_blocks, 256, 0, stream>>>(
        coords, px0, py0, pz0, px1, py1, pz1, px2, py2, pz2, out);
  }
}

// Round 7
// 346.184 us; speedup vs baseline: 4.0413x; 1.1168x over previous
//
#include <hip/hip_runtime.h>
#include <hip/hip_fp16.h>

#define NPTS 500000
#define NBINS 32768   // 32^3 Morton bins
#define NSUPER 16384  // bins merged in pairs along x

// Planes stored fp16, pre-scaled by 1024 (exact pow2); final result * 1/1024.
#define PLANE_SCALE 1024.0f
#define INV_PLANE_SCALE 0.0009765625f

// ---------------------------------------------------------------------------
// Keys cubic conv weights, a = -0.75, taps at offsets [-1,0,1,2], t in [0,1)
// ---------------------------------------------------------------------------
__device__ __forceinline__ void cubic_w(float t, float w[4]) {
  const float a = -0.75f;
  const float t1 = t + 1.0f;
  w[0] = ((a * t1 - 5.0f * a) * t1 + 8.0f * a) * t1 - 4.0f * a;
  w[1] = ((a + 2.0f) * t - (a + 3.0f)) * t * t + 1.0f;
  const float u = 1.0f - t;
  w[2] = ((a + 2.0f) * u - (a + 3.0f)) * u * u + 1.0f;
  const float t2 = 2.0f - t;
  w[3] = ((a * t2 - 5.0f * a) * t2 + 8.0f * a) * t2 - 4.0f * a;
}

// ---------------------------------------------------------------------------
// Transpose (C,H,W) fp32 -> (H*W, C) fp16*1024, 3 planes batched on blockIdx.y
// ---------------------------------------------------------------------------
__global__ __launch_bounds__(256) void transpose_chw_hwc_f16(
    const float* __restrict__ p0, const float* __restrict__ p1,
    const float* __restrict__ p2, __half* __restrict__ dst, int HW) {
  __shared__ float lds[64][65];
  const float* src = (blockIdx.y == 0) ? p0 : ((blockIdx.y == 1) ? p1 : p2);
  __half* out = dst + (size_t)blockIdx.y * (size_t)HW * 64;
  const int pixBase = blockIdx.x * 64;
  const int tid = threadIdx.x;
  const int lane = tid & 63;
  const int quad = tid >> 6;
#pragma unroll
  for (int k = 0; k < 16; ++k) {
    const int c = k * 4 + quad;
    lds[c][lane] = src[(size_t)c * HW + pixBase + lane];
  }
  __syncthreads();
#pragma unroll
  for (int k = 0; k < 16; ++k) {
    const int pp = k * 4 + quad;
    out[(size_t)(pixBase + pp) * 64 + lane] =
        __float2half(lds[lane][pp] * PLANE_SCALE);
  }
}

// ---------------------------------------------------------------------------
// Morton binning helpers
// ---------------------------------------------------------------------------
__device__ __forceinline__ unsigned spread3(unsigned v) {
  return (v & 1u) | ((v & 2u) << 2) | ((v & 4u) << 4) | ((v & 8u) << 6) |
         ((v & 16u) << 8);
}

__device__ __forceinline__ unsigned compact3(unsigned v) {
  return (v & 1u) | ((v >> 2) & 2u) | ((v >> 4) & 4u) | ((v >> 6) & 8u) |
         ((v >> 8) & 16u);
}

__device__ __forceinline__ int bin_of(float cx, float cy, float cz) {
  int xq = (int)((cx + 1.0f) * 16.0f);
  int yq = (int)((cy + 1.0f) * 16.0f);
  int zq = (int)((cz + 1.0f) * 16.0f);
  xq = xq < 0 ? 0 : (xq > 31 ? 31 : xq);
  yq = yq < 0 ? 0 : (yq > 31 ? 31 : yq);
  zq = zq < 0 ? 0 : (zq > 31 ? 31 : zq);
  return (int)(spread3((unsigned)xq) | (spread3((unsigned)yq) << 1) |
               (spread3((unsigned)zq) << 2));
}

__global__ __launch_bounds__(256) void bin_count(
    const float* __restrict__ coords, int* __restrict__ counts) {
  const int pt = blockIdx.x * 256 + threadIdx.x;
  if (pt >= NPTS) return;
  const int b = bin_of(coords[pt * 3], coords[pt * 3 + 1], coords[pt * 3 + 2]);
  atomicAdd(&counts[b], 1);
}

__global__ __launch_bounds__(1024) void bin_scan(
    const int* __restrict__ counts, int* __restrict__ cursor) {
  __shared__ int lds[1024];
  const int t = threadIdx.x;
  const int base = t * 32;
  int s = 0;
#pragma unroll
  for (int i = 0; i < 32; ++i) s += counts[base + i];
  lds[t] = s;
  __syncthreads();
  int own = s;
  for (int off = 1; off < 1024; off <<= 1) {
    int v = (t >= off) ? lds[t - off] : 0;
    __syncthreads();
    lds[t] += v;
    __syncthreads();
  }
  int run = lds[t] - own;
#pragma unroll
  for (int i = 0; i < 32; ++i) {
    cursor[base + i] = run;
    run += counts[base + i];
  }
}

// ---------------------------------------------------------------------------
// Scatter fused with weight precompute. Per point, per scale, 32-B record:
// {wx01, wx23, wy01, wy23, wz01, wz23, relx*8|rely<<8|relz<<16, pt}
// ---------------------------------------------------------------------------
__global__ __launch_bounds__(256) void bin_scatter_prep(
    const float* __restrict__ coords, int* __restrict__ cursor,
    uint4* __restrict__ wrec) {
  const int pt = blockIdx.x * 256 + threadIdx.x;
  if (pt >= NPTS) return;
  const float x = coords[pt * 3], y = coords[pt * 3 + 1],
              z = coords[pt * 3 + 2];
  const int b = bin_of(x, y, z);
  const int pos = atomicAdd(&cursor[b], 1);

  const int qx0 = ((int)compact3((unsigned)b)) & ~1;
  const int qy = (int)compact3((unsigned)b >> 1);
  const int qz = (int)compact3((unsigned)b >> 2);
  const float vin[3] = {x, y, z};

#pragma unroll
  for (int s = 0; s < 3; ++s) {
    const int W = (s == 0) ? 256 : ((s == 1) ? 128 : 64);
    const float hw = 0.5f * (float)(W - 1);
    const int fb[3] = {(int)floorf((1.0f + (float)qx0 * 0.03125f) * hw),
                       (int)floorf((1.0f + (float)qy * 0.03125f) * hw),
                       (int)floorf((1.0f + (float)qz * 0.03125f) * hw)};
    uint wp[6];
    int rel[3];
#pragma unroll
    for (int a = 0; a < 3; ++a) {
      const float c = (vin[a] + 1.0f) * 0.5f;
      const float gx = (c + 1.0f) * 0.5f * (float)(W - 1);
      const float x0f = floorf(gx);
      float w[4];
      cubic_w(gx - x0f, w);
      int r = (int)x0f - fb[a];
      const int rmax = (a == 0) ? 12 : 4;
      r = r < 0 ? 0 : (r > rmax ? rmax : r);
      rel[a] = r;
      const __half2 lo = __halves2half2(__float2half(w[0]), __float2half(w[1]));
      const __half2 hi = __halves2half2(__float2half(w[2]), __float2half(w[3]));
      wp[a * 2] = *(const uint*)&lo;
      wp[a * 2 + 1] = *(const uint*)&hi;
    }
    uint4* dst = wrec + ((size_t)s * NPTS + pos) * 2;
    dst[0] = make_uint4(wp[0], wp[1], wp[2], wp[3]);
    dst[1] = make_uint4(
        wp[4], wp[5],
        (uint)(rel[0] * 8) | ((uint)rel[1] << 8) | ((uint)rel[2] << 16),
        (uint)pt);
  }
}

// ---------------------------------------------------------------------------
// Superbin sampling: one block per (superbin, scale). LDS windows:
// XY 8y x 16x, YZ 8z x 8y, XZ 8z x 16x; 8 ch-groups of uint4 -> 40 KB.
// Bank permutation via cg^row applied on the GLOBAL source during staging
// (linear LDS dest, global_load_lds-compatible) and on the read index.
// ---------------------------------------------------------------------------
__global__ __launch_bounds__(256, 4) void sample_super(
    const uint4* __restrict__ wrec, const ushort* __restrict__ tp,
    const int* __restrict__ endc, float* __restrict__ out) {
  __shared__ uint4 win[2560];

  const int orig = blockIdx.x;
  const int sb = (orig & 7) * (NSUPER / 8) + (orig >> 3);
  const int b0 = sb * 2;
  const int start = (b0 == 0) ? 0 : endc[b0 - 1];
  const int end = endc[b0 + 1];
  if (start >= end) return;

  const int s = blockIdx.y;
  const int W = (s == 0) ? 256 : ((s == 1) ? 128 : 64);
  const size_t sbase = (s == 0) ? 0 : ((s == 1) ? 12582912 : 15728640);
  const size_t psz = (size_t)W * W * 64;
  const float hw = 0.5f * (float)(W - 1);

  const int qx0 = ((int)compact3((unsigned)b0)) & ~1;
  const int qy = (int)compact3((unsigned)b0 >> 1);
  const int qz = (int)compact3((unsigned)b0 >> 2);
  const int wbx = (int)floorf((1.0f + (float)qx0 * 0.03125f) * hw) - 1;
  const int wby = (int)floorf((1.0f + (float)qy * 0.03125f) * hw) - 1;
  const int wbz = (int)floorf((1.0f + (float)qz * 0.03125f) * hw) - 1;

  const char* tpb = (const char*)(tp + sbase);
  const int tid = threadIdx.x;
  const int wavebase0 = tid & ~63;  // wave-uniform
#pragma unroll
  for (int k = 0; k < 10; ++k) {
    const int chunk = tid + k * 256;
    int row, col, grow, gcol, p;
    if (chunk < 1024) {  // XY: row=y, col=x (16 wide)
      p = 0;
      row = chunk >> 7;
      col = (chunk >> 3) & 15;
      grow = wby + row;
      gcol = wbx + col;
    } else if (chunk < 1536) {  // YZ: row=z, col=y (8 wide)
      const int q = chunk - 1024;
      p = 1;
      row = q >> 6;
      col = (q >> 3) & 7;
      grow = wbz + row;
      gcol = wby + col;
    } else {  // XZ: row=z, col=x (16 wide)
      const int q = chunk - 1536;
      p = 2;
      row = q >> 7;
      col = (q >> 3) & 15;
      grow = wbz + row;
      gcol = wbx + col;
    }
    grow = grow < 0 ? 0 : (grow > W - 1 ? W - 1 : grow);
    gcol = gcol < 0 ? 0 : (gcol > W - 1 ? W - 1 : gcol);
    // pre-swizzled SOURCE channel group; LDS dest stays linear
    const int cg_src = (chunk & 7) ^ (row & 7);
    const char* src =
        tpb + (size_t)p * psz * 2 + ((size_t)grow * W + gcol) * 128 +
        cg_src * 16;
#if __has_builtin(__builtin_amdgcn_global_load_lds)
    __builtin_amdgcn_global_load_lds(
        (const uint*)src, (uint*)&win[k * 256 + wavebase0], 16, 0, 0);
#else
    win[chunk] = *reinterpret_cast<const uint4*>(src);
#endif
  }
  __syncthreads();

  const int lanegrp = tid >> 3;  // 32 point slots per iteration
  const int cg = tid & 7;        // 8 channels per lane

  for (int i0 = start; i0 < end; i0 += 32) {
    const int slot = i0 + lanegrp;
    if (slot >= end) break;
    const uint4 r0 = wrec[((size_t)s * NPTS + slot) * 2];
    const uint4 r1 = wrec[((size_t)s * NPTS + slot) * 2 + 1];
    const int pt = (int)r1.w;
    const int relx8 = (int)(r1.z & 255u);  // pre-multiplied by 8
    const int rely = (int)((r1.z >> 8) & 255u);
    const int relz = (int)((r1.z >> 16) & 255u);
    const int rely8 = rely << 3;

    __half2 wx[4], wy[4], wz[4];
    {
      const __half2 hx01 = *(const __half2*)&r0.x;
      const __half2 hx23 = *(const __half2*)&r0.y;
      const __half2 hy01 = *(const __half2*)&r0.z;
      const __half2 hy23 = *(const __half2*)&r0.w;
      const __half2 hz01 = *(const __half2*)&r1.x;
      const __half2 hz23 = *(const __half2*)&r1.y;
      wx[0] = __half2half2(__low2half(hx01));
      wx[1] = __half2half2(__high2half(hx01));
      wx[2] = __half2half2(__low2half(hx23));
      wx[3] = __half2half2(__high2half(hx23));
      wy[0] = __half2half2(__low2half(hy01));
      wy[1] = __half2half2(__high2half(hy01));
      wy[2] = __half2half2(__low2half(hy23));
      wy[3] = __half2half2(__high2half(hy23));
      wz[0] = __half2half2(__low2half(hz01));
      wz[1] = __half2half2(__high2half(hz01));
      wz[2] = __half2half2(__low2half(hz23));
      wz[3] = __half2half2(__high2half(hz23));
    }

    __half2 a0 = __float2half2_rn(0.0f), a1 = a0, a2 = a0, a3 = a0;

#define ROWTAPS(BASEPTR, CW, RW_j)                                    \
  {                                                                   \
    const uint4* bp = (BASEPTR);                                      \
    __half2 q0 = __float2half2_rn(0.0f), q1 = q0, q2 = q0, q3 = q0;   \
    _Pragma("unroll") for (int i = 0; i < 4; ++i) {                   \
      const uint4 v = bp[8 * i];                                      \
      q0 = __hfma2(CW[i], *(const __half2*)&v.x, q0);                 \
      q1 = __hfma2(CW[i], *(const __half2*)&v.y, q1);                 \
      q2 = __hfma2(CW[i], *(const __half2*)&v.z, q2);                 \
      q3 = __hfma2(CW[i], *(const __half2*)&v.w, q3);                 \
    }                                                                 \
    a0 = __hfma2(RW_j, q0, a0);                                       \
    a1 = __hfma2(RW_j, q1, a1);                                       \
    a2 = __hfma2(RW_j, q2, a2);                                       \
    a3 = __hfma2(RW_j, q3, a3);                                       \
  }

#pragma unroll
    for (int j = 0; j < 4; ++j) {  // XY: row=y, col=x
      const int row = rely + j;
      ROWTAPS(&win[row * 128 + (cg ^ row) + relx8], wx, wy[j]);
    }
#pragma unroll
    for (int j = 0; j < 4; ++j) {  // YZ: row=z, col=y
      const int row = relz + j;
      ROWTAPS(&win[1024 + row * 64 + (cg ^ row) + rely8], wy, wz[j]);
    }
#pragma unroll
    for (int j = 0; j < 4; ++j) {  // XZ: row=z, col=x
      const int row = relz + j;
      ROWTAPS(&win[1536 + row * 128 + (cg ^ row) + relx8], wx, wz[j]);
    }
#undef ROWTAPS

    const float2 f0 = __half22float2(a0);
    const float2 f1 = __half22float2(a1);
    const float2 f2 = __half22float2(a2);
    const float2 f3 = __half22float2(a3);
    float* optr = out + (size_t)pt * 192 + s * 64 + cg * 8;
    *reinterpret_cast<float4*>(optr) =
        make_float4(f0.x * INV_PLANE_SCALE, f0.y * INV_PLANE_SCALE,
                    f1.x * INV_PLANE_SCALE, f1.y * INV_PLANE_SCALE);
    *reinterpret_cast<float4*>(optr + 4) =
        make_float4(f2.x * INV_PLANE_SCALE, f2.y * INV_PLANE_SCALE,
                    f3.x * INV_PLANE_SCALE, f3.y * INV_PLANE_SCALE);
  }
}

// ---------------------------------------------------------------------------
// Fallback: fp32 direct from (C,H,W) if workspace too small.
// ---------------------------------------------------------------------------
__device__ __forceinline__ void sample_acc_chw(const float* __restrict__ plane,
                                               int W, float gx, float gy,
                                               int cg, float4& acc) {
  const float x = (gx + 1.0f) * 0.5f * (float)(W - 1);
  const float y = (gy + 1.0f) * 0.5f * (float)(W - 1);
  const float x0f = floorf(x), y0f = floorf(y);
  float wx[4], wy[4];
  cubic_w(x - x0f, wx);
  cubic_w(y - y0f, wy);
  const int x0 = (int)x0f, y0 = (int)y0f;
  int ix[4], iy[4];
#pragma unroll
  for (int i = 0; i < 4; ++i) {
    int xi = x0 - 1 + i;
    ix[i] = xi < 0 ? 0 : (xi > W - 1 ? W - 1 : xi);
    int yi = y0 - 1 + i;
    iy[i] = yi < 0 ? 0 : (yi > W - 1 ? W - 1 : yi);
  }
  const size_t HW = (size_t)W * W;
  float r[4] = {acc.x, acc.y, acc.z, acc.w};
#pragma unroll
  for (int cc = 0; cc < 4; ++cc) {
    const float* pc = plane + (size_t)(cg * 4 + cc) * HW;
    float a = 0.f;
#pragma unroll
    for (int j = 0; j < 4; ++j) {
      const float* rb = pc + (size_t)iy[j] * W;
      float row = 0.f;
#pragma unroll
      for (int i = 0; i < 4; ++i) row += wx[i] * rb[ix[i]];
      a += wy[j] * row;
    }
    r[cc] += a;
  }
  acc = make_float4(r[0], r[1], r[2], r[3]);
}

__global__ __launch_bounds__(256) void sample_fallback(
    const float* __restrict__ coords, const float* __restrict__ px0,
    const float* __restrict__ py0, const float* __restrict__ pz0,
    const float* __restrict__ px1, const float* __restrict__ py1,
    const float* __restrict__ pz1, const float* __restrict__ px2,
    const float* __restrict__ py2, const float* __restrict__ pz2,
    float* __restrict__ out) {
  const int t = blockIdx.x * 256 + threadIdx.x;
  const int pt = t >> 4;
  const int cg = t & 15;
  if (pt >= NPTS) return;
  const float cx = (coords[pt * 3 + 0] + 1.0f) * 0.5f;
  const float cy = (coords[pt * 3 + 1] + 1.0f) * 0.5f;
  const float cz = (coords[pt * 3 + 2] + 1.0f) * 0.5f;
  const float* xs[3] = {px0, px1, px2};
  const float* ys[3] = {py0, py1, py2};
  const float* zs[3] = {pz0, pz1, pz2};
  const int sw[3] = {256, 128, 64};
  float* optr = out + (size_t)pt * 192 + cg * 4;
#pragma unroll
  for (int s = 0; s < 3; ++s) {
    const int W = sw[s];
    float4 acc = make_float4(0.f, 0.f, 0.f, 0.f);
    sample_acc_chw(xs[s], W, cx, cy, cg, acc);
    sample_acc_chw(ys[s], W, cy, cz, cg, acc);
    sample_acc_chw(zs[s], W, cx, cz, cg, acc);
    *reinterpret_cast<float4*>(optr + s * 64) = acc;
  }
}

// ---------------------------------------------------------------------------
extern "C" void kernel_launch(void* const* d_in, const int* in_sizes, int n_in,
                              void* d_out, int out_size, void* d_ws,
                              size_t ws_size, hipStream_t stream) {
  const float* coords = (const float*)d_in[0];
  const float* px0 = (const float*)d_in[1];
  const float* py0 = (const float*)d_in[2];
  const float* pz0 = (const float*)d_in[3];
  const float* px1 = (const float*)d_in[4];
  const float* py1 = (const float*)d_in[5];
  const float* pz1 = (const float*)d_in[6];
  const float* px2 = (const float*)d_in[7];
  const float* py2 = (const float*)d_in[8];
  const float* pz2 = (const float*)d_in[9];
  float* out = (float*)d_out;

  // ws layout (bytes): f16 planes, counts, end-cursor, weight records
  const size_t TP_BYTES = 33030144;
  const size_t CNT_OFF = TP_BYTES;           // 131072 B
  const size_t CUR_OFF = CNT_OFF + 131072;   // 131072 B
  const size_t REC_OFF = CUR_OFF + 131072;   // 48,000,000 B
  const size_t NEEDED = REC_OFF + (size_t)NPTS * 3 * 32;

  if (ws_size >= NEEDED) {
    __half* tp = (__half*)d_ws;
    int* counts = (int*)((char*)d_ws + CNT_OFF);
    int* cursor = (int*)((char*)d_ws + CUR_OFF);
    uint4* wrec = (uint4*)((char*)d_ws + REC_OFF);

    transpose_chw_hwc_f16<<<dim3(65536 / 64, 3), 256, 0, stream>>>(
        px0, py0, pz0, tp + 0, 65536);
    transpose_chw_hwc_f16<<<dim3(16384 / 64, 3), 256, 0, stream>>>(
        px1, py1, pz1, tp + 12582912, 16384);
    transpose_chw_hwc_f16<<<dim3(4096 / 64, 3), 256, 0, stream>>>(
        px2, py2, pz2, tp + 15728640, 4096);

    hipMemsetAsync(counts, 0, NBINS * sizeof(int), stream);
    const int pblocks = (NPTS + 255) / 256;
    bin_count<<<pblocks, 256, 0, stream>>>(coords, counts);
    bin_scan<<<1, 1024, 0, stream>>>(counts, cursor);
    bin_scatter_prep<<<pblocks, 256, 0, stream>>>(coords, cursor, wrec);
    // cursor[b] now == end offset of bin b

    sample_super<<<dim3(NSUPER, 3), 256, 0, stream>>>(
        wrec, (const ushort*)tp, cursor, out);
  } else {
    const int sample_blocks = (NPTS * 16 + 255) / 256;
    sample_fallback<<<sample_blocks, 256, 0, stream>>>(
        coords, px0, py0, pz0, px1, py1, pz1, px2, py2, pz2, out);
  }
}

// Round 8
// 334.430 us; speedup vs baseline: 4.1834x; 1.0351x over previous
//
#include <hip/hip_runtime.h>
#include <hip/hip_fp16.h>

#define NPTS 500000
#define NBINS 32768   // 32^3 Morton bins
#define NSUPER 8192   // 4 bins merged (2x2 in x,y)

// Planes stored fp16, pre-scaled by 1024 (exact pow2); final result * 1/1024.
#define PLANE_SCALE 1024.0f
#define INV_PLANE_SCALE 0.0009765625f

// ---------------------------------------------------------------------------
// Keys cubic conv weights, a = -0.75, taps at offsets [-1,0,1,2], t in [0,1)
// ---------------------------------------------------------------------------
__device__ __forceinline__ void cubic_w(float t, float w[4]) {
  const float a = -0.75f;
  const float t1 = t + 1.0f;
  w[0] = ((a * t1 - 5.0f * a) * t1 + 8.0f * a) * t1 - 4.0f * a;
  w[1] = ((a + 2.0f) * t - (a + 3.0f)) * t * t + 1.0f;
  const float u = 1.0f - t;
  w[2] = ((a + 2.0f) * u - (a + 3.0f)) * u * u + 1.0f;
  const float t2 = 2.0f - t;
  w[3] = ((a * t2 - 5.0f * a) * t2 + 8.0f * a) * t2 - 4.0f * a;
}

// ---------------------------------------------------------------------------
// Transpose (C,H,W) fp32 -> (H*W, C) fp16*1024, 3 planes batched on blockIdx.y
// ---------------------------------------------------------------------------
__global__ __launch_bounds__(256) void transpose_chw_hwc_f16(
    const float* __restrict__ p0, const float* __restrict__ p1,
    const float* __restrict__ p2, __half* __restrict__ dst, int HW) {
  __shared__ float lds[64][65];
  const float* src = (blockIdx.y == 0) ? p0 : ((blockIdx.y == 1) ? p1 : p2);
  __half* out = dst + (size_t)blockIdx.y * (size_t)HW * 64;
  const int pixBase = blockIdx.x * 64;
  const int tid = threadIdx.x;
  const int lane = tid & 63;
  const int quad = tid >> 6;
#pragma unroll
  for (int k = 0; k < 16; ++k) {
    const int c = k * 4 + quad;
    lds[c][lane] = src[(size_t)c * HW + pixBase + lane];
  }
  __syncthreads();
#pragma unroll
  for (int k = 0; k < 16; ++k) {
    const int pp = k * 4 + quad;
    out[(size_t)(pixBase + pp) * 64 + lane] =
        __float2half(lds[lane][pp] * PLANE_SCALE);
  }
}

// ---------------------------------------------------------------------------
// Morton binning helpers
// ---------------------------------------------------------------------------
__device__ __forceinline__ unsigned spread3(unsigned v) {
  return (v & 1u) | ((v & 2u) << 2) | ((v & 4u) << 4) | ((v & 8u) << 6) |
         ((v & 16u) << 8);
}

__device__ __forceinline__ unsigned compact3(unsigned v) {
  return (v & 1u) | ((v >> 2) & 2u) | ((v >> 4) & 4u) | ((v >> 6) & 8u) |
         ((v >> 8) & 16u);
}

__device__ __forceinline__ int bin_of(float cx, float cy, float cz) {
  int xq = (int)((cx + 1.0f) * 16.0f);
  int yq = (int)((cy + 1.0f) * 16.0f);
  int zq = (int)((cz + 1.0f) * 16.0f);
  xq = xq < 0 ? 0 : (xq > 31 ? 31 : xq);
  yq = yq < 0 ? 0 : (yq > 31 ? 31 : yq);
  zq = zq < 0 ? 0 : (zq > 31 ? 31 : zq);
  return (int)(spread3((unsigned)xq) | (spread3((unsigned)yq) << 1) |
               (spread3((unsigned)zq) << 2));
}

__global__ __launch_bounds__(256) void bin_count(
    const float* __restrict__ coords, int* __restrict__ counts) {
  const int pt = blockIdx.x * 256 + threadIdx.x;
  if (pt >= NPTS) return;
  const int b = bin_of(coords[pt * 3], coords[pt * 3 + 1], coords[pt * 3 + 2]);
  atomicAdd(&counts[b], 1);
}

__global__ __launch_bounds__(1024) void bin_scan(
    const int* __restrict__ counts, int* __restrict__ cursor) {
  __shared__ int lds[1024];
  const int t = threadIdx.x;
  const int base = t * 32;
  int s = 0;
#pragma unroll
  for (int i = 0; i < 32; ++i) s += counts[base + i];
  lds[t] = s;
  __syncthreads();
  int own = s;
  for (int off = 1; off < 1024; off <<= 1) {
    int v = (t >= off) ? lds[t - off] : 0;
    __syncthreads();
    lds[t] += v;
    __syncthreads();
  }
  int run = lds[t] - own;
#pragma unroll
  for (int i = 0; i < 32; ++i) {
    cursor[base + i] = run;
    run += counts[base + i];
  }
}

// ---------------------------------------------------------------------------
// Scatter fused with weight precompute. Per point, per scale, 32-B record:
// {wx01, wx23, wy01, wy23, wz01, wz23, relx*4|rely*4<<8|relz<<16, pt}
// rel are window-relative tap bases for the 2x2-merged superbin window.
// ---------------------------------------------------------------------------
__global__ __launch_bounds__(256) void bin_scatter_prep(
    const float* __restrict__ coords, int* __restrict__ cursor,
    uint4* __restrict__ wrec) {
  const int pt = blockIdx.x * 256 + threadIdx.x;
  if (pt >= NPTS) return;
  const float x = coords[pt * 3], y = coords[pt * 3 + 1],
              z = coords[pt * 3 + 2];
  const int b = bin_of(x, y, z);
  const int pos = atomicAdd(&cursor[b], 1);

  const int qx0 = ((int)compact3((unsigned)b)) & ~1;
  const int qy0 = ((int)compact3((unsigned)b >> 1)) & ~1;
  const int qz = (int)compact3((unsigned)b >> 2);
  const float vin[3] = {x, y, z};

#pragma unroll
  for (int s = 0; s < 3; ++s) {
    const int W = (s == 0) ? 256 : ((s == 1) ? 128 : 64);
    const float hw = 0.5f * (float)(W - 1);
    const int fb[3] = {(int)floorf((1.0f + (float)qx0 * 0.03125f) * hw),
                       (int)floorf((1.0f + (float)qy0 * 0.03125f) * hw),
                       (int)floorf((1.0f + (float)qz * 0.03125f) * hw)};
    uint wp[6];
    int rel[3];
#pragma unroll
    for (int a = 0; a < 3; ++a) {
      const float c = (vin[a] + 1.0f) * 0.5f;
      const float gx = (c + 1.0f) * 0.5f * (float)(W - 1);
      const float x0f = floorf(gx);
      float w[4];
      cubic_w(gx - x0f, w);
      int r = (int)x0f - fb[a];
      const int rmax = (a == 2) ? 4 : 12;
      r = r < 0 ? 0 : (r > rmax ? rmax : r);
      rel[a] = r;
      const __half2 lo = __halves2half2(__float2half(w[0]), __float2half(w[1]));
      const __half2 hi = __halves2half2(__float2half(w[2]), __float2half(w[3]));
      wp[a * 2] = *(const uint*)&lo;
      wp[a * 2 + 1] = *(const uint*)&hi;
    }
    uint4* dst = wrec + ((size_t)s * NPTS + pos) * 2;
    dst[0] = make_uint4(wp[0], wp[1], wp[2], wp[3]);
    dst[1] = make_uint4(
        wp[4], wp[5],
        (uint)(rel[0] * 4) | ((uint)(rel[1] * 4) << 8) | ((uint)rel[2] << 16),
        (uint)pt);
  }
}

// ---------------------------------------------------------------------------
// Superbin sampling: block per (superbin, scale, ch-half). 32 ch per block.
// LDS: XY 16y x 16x, YZ 8z x 16y, XZ 8z x 16x; 4 cg of uint4 -> 32 KB.
// Bank permutation cg^row applied on GLOBAL source during staging (linear
// LDS dest per global_load_lds) and on the read index.
// ---------------------------------------------------------------------------
__global__ __launch_bounds__(256, 5) void sample_super(
    const uint4* __restrict__ wrec, const ushort* __restrict__ tp,
    const int* __restrict__ endc, float* __restrict__ out) {
  __shared__ uint4 win[2048];

  const int orig = blockIdx.x;
  const int sb = (orig & 7) * (NSUPER / 8) + (orig >> 3);
  const int b0 = sb * 4;  // 4 consecutive Morton bins = 2x2 in (x,y)
  const int start = (b0 == 0) ? 0 : endc[b0 - 1];
  const int end = endc[b0 + 3];
  if (start >= end) return;

  const int s = blockIdx.y;
  const int h = blockIdx.z;  // channel half: 0 or 1
  const int W = (s == 0) ? 256 : ((s == 1) ? 128 : 64);
  const size_t sbase = (s == 0) ? 0 : ((s == 1) ? 12582912 : 15728640);
  const size_t psz = (size_t)W * W * 64;
  const float hw = 0.5f * (float)(W - 1);

  const int qx0 = ((int)compact3((unsigned)b0)) & ~1;
  const int qy0 = ((int)compact3((unsigned)b0 >> 1)) & ~1;
  const int qz = (int)compact3((unsigned)b0 >> 2);
  const int wbx = (int)floorf((1.0f + (float)qx0 * 0.03125f) * hw) - 1;
  const int wby = (int)floorf((1.0f + (float)qy0 * 0.03125f) * hw) - 1;
  const int wbz = (int)floorf((1.0f + (float)qz * 0.03125f) * hw) - 1;

  const char* tpb = (const char*)(tp + sbase) + h * 64;  // 32-ch half
  const int tid = threadIdx.x;
#pragma unroll
  for (int k = 0; k < 8; ++k) {
    const int chunk = tid + k * 256;
    int row, col, grow, gcol, p;
    if (chunk < 1024) {  // XY: row=y (16), col=x (16)
      p = 0;
      row = chunk >> 6;
      col = (chunk >> 2) & 15;
      grow = wby + row;
      gcol = wbx + col;
    } else if (chunk < 1536) {  // YZ: row=z (8), col=y (16)
      const int q = chunk - 1024;
      p = 1;
      row = q >> 6;
      col = (q >> 2) & 15;
      grow = wbz + row;
      gcol = wby + col;
    } else {  // XZ: row=z (8), col=x (16)
      const int q = chunk - 1536;
      p = 2;
      row = q >> 6;
      col = (q >> 2) & 15;
      grow = wbz + row;
      gcol = wbx + col;
    }
    grow = grow < 0 ? 0 : (grow > W - 1 ? W - 1 : grow);
    gcol = gcol < 0 ? 0 : (gcol > W - 1 ? W - 1 : gcol);
    // pre-swizzled SOURCE channel group; LDS dest stays linear
    const int cg_src = (chunk & 3) ^ (row & 3);
    const char* src = tpb + (size_t)p * psz * 2 +
                      ((size_t)grow * W + gcol) * 128 + cg_src * 16;
#if __has_builtin(__builtin_amdgcn_global_load_lds)
    __builtin_amdgcn_global_load_lds(
        (const uint*)src, (uint*)&win[k * 256 + (tid & ~63)], 16, 0, 0);
#else
    win[chunk] = *reinterpret_cast<const uint4*>(src);
#endif
  }
  __syncthreads();

  const int lanegrp = tid >> 2;  // 64 point slots per block iteration
  const int cg = tid & 3;        // 8 channels per lane (of this 32-ch half)

  for (int i0 = start; i0 < end; i0 += 64) {
    const int slot = i0 + lanegrp;
    if (slot >= end) break;
    const uint4 r0 = wrec[((size_t)s * NPTS + slot) * 2];
    const uint4 r1 = wrec[((size_t)s * NPTS + slot) * 2 + 1];
    const int pt = (int)r1.w;
    const int relx4 = (int)(r1.z & 255u);         // rel_x * 4
    const int rely4 = (int)((r1.z >> 8) & 255u);  // rel_y * 4
    const int relz = (int)((r1.z >> 16) & 255u);
    const int rely = rely4 >> 2;

    __half2 wx[4], wy[4], wz[4];
    {
      const __half2 hx01 = *(const __half2*)&r0.x;
      const __half2 hx23 = *(const __half2*)&r0.y;
      const __half2 hy01 = *(const __half2*)&r0.z;
      const __half2 hy23 = *(const __half2*)&r0.w;
      const __half2 hz01 = *(const __half2*)&r1.x;
      const __half2 hz23 = *(const __half2*)&r1.y;
      wx[0] = __half2half2(__low2half(hx01));
      wx[1] = __half2half2(__high2half(hx01));
      wx[2] = __half2half2(__low2half(hx23));
      wx[3] = __half2half2(__high2half(hx23));
      wy[0] = __half2half2(__low2half(hy01));
      wy[1] = __half2half2(__high2half(hy01));
      wy[2] = __half2half2(__low2half(hy23));
      wy[3] = __half2half2(__high2half(hy23));
      wz[0] = __half2half2(__low2half(hz01));
      wz[1] = __half2half2(__high2half(hz01));
      wz[2] = __half2half2(__low2half(hz23));
      wz[3] = __half2half2(__high2half(hz23));
    }

    __half2 a0 = __float2half2_rn(0.0f), a1 = a0, a2 = a0, a3 = a0;

#define ROWTAPS(BASEPTR, CW, RW_j)                                    \
  {                                                                   \
    const uint4* bp = (BASEPTR);                                      \
    __half2 q0 = __float2half2_rn(0.0f), q1 = q0, q2 = q0, q3 = q0;   \
    _Pragma("unroll") for (int i = 0; i < 4; ++i) {                   \
      const uint4 v = bp[4 * i];                                      \
      q0 = __hfma2(CW[i], *(const __half2*)&v.x, q0);                 \
      q1 = __hfma2(CW[i], *(const __half2*)&v.y, q1);                 \
      q2 = __hfma2(CW[i], *(const __half2*)&v.z, q2);                 \
      q3 = __hfma2(CW[i], *(const __half2*)&v.w, q3);                 \
    }                                                                 \
    a0 = __hfma2(RW_j, q0, a0);                                       \
    a1 = __hfma2(RW_j, q1, a1);                                       \
    a2 = __hfma2(RW_j, q2, a2);                                       \
    a3 = __hfma2(RW_j, q3, a3);                                       \
  }

#pragma unroll
    for (int j = 0; j < 4; ++j) {  // XY: row=y, col=x
      const int row = rely + j;
      ROWTAPS(&win[row * 64 + relx4 + (cg ^ (row & 3))], wx, wy[j]);
    }
#pragma unroll
    for (int j = 0; j < 4; ++j) {  // YZ: row=z, col=y
      const int row = relz + j;
      ROWTAPS(&win[1024 + row * 64 + rely4 + (cg ^ (row & 3))], wy, wz[j]);
    }
#pragma unroll
    for (int j = 0; j < 4; ++j) {  // XZ: row=z, col=x
      const int row = relz + j;
      ROWTAPS(&win[1536 + row * 64 + relx4 + (cg ^ (row & 3))], wx, wz[j]);
    }
#undef ROWTAPS

    const float2 f0 = __half22float2(a0);
    const float2 f1 = __half22float2(a1);
    const float2 f2 = __half22float2(a2);
    const float2 f3 = __half22float2(a3);
    float* optr = out + (size_t)pt * 192 + s * 64 + h * 32 + cg * 8;
    *reinterpret_cast<float4*>(optr) =
        make_float4(f0.x * INV_PLANE_SCALE, f0.y * INV_PLANE_SCALE,
                    f1.x * INV_PLANE_SCALE, f1.y * INV_PLANE_SCALE);
    *reinterpret_cast<float4*>(optr + 4) =
        make_float4(f2.x * INV_PLANE_SCALE, f2.y * INV_PLANE_SCALE,
                    f3.x * INV_PLANE_SCALE, f3.y * INV_PLANE_SCALE);
  }
}

// ---------------------------------------------------------------------------
// Fallback: fp32 direct from (C,H,W) if workspace too small.
// ---------------------------------------------------------------------------
__device__ __forceinline__ void sample_acc_chw(const float* __restrict__ plane,
                                               int W, float gx, float gy,
                                               int cg, float4& acc) {
  const float x = (gx + 1.0f) * 0.5f * (float)(W - 1);
  const float y = (gy + 1.0f) * 0.5f * (float)(W - 1);
  const float x0f = floorf(x), y0f = floorf(y);
  float wx[4], wy[4];
  cubic_w(x - x0f, wx);
  cubic_w(y - y0f, wy);
  const int x0 = (int)x0f, y0 = (int)y0f;
  int ix[4], iy[4];
#pragma unroll
  for (int i = 0; i < 4; ++i) {
    int xi = x0 - 1 + i;
    ix[i] = xi < 0 ? 0 : (xi > W - 1 ? W - 1 : xi);
    int yi = y0 - 1 + i;
    iy[i] = yi < 0 ? 0 : (yi > W - 1 ? W - 1 : yi);
  }
  const size_t HW = (size_t)W * W;
  float r[4] = {acc.x, acc.y, acc.z, acc.w};
#pragma unroll
  for (int cc = 0; cc < 4; ++cc) {
    const float* pc = plane + (size_t)(cg * 4 + cc) * HW;
    float a = 0.f;
#pragma unroll
    for (int j = 0; j < 4; ++j) {
      const float* rb = pc + (size_t)iy[j] * W;
      float row = 0.f;
#pragma unroll
      for (int i = 0; i < 4; ++i) row += wx[i] * rb[ix[i]];
      a += wy[j] * row;
    }
    r[cc] += a;
  }
  acc = make_float4(r[0], r[1], r[2], r[3]);
}

__global__ __launch_bounds__(256) void sample_fallback(
    const float* __restrict__ coords, const float* __restrict__ px0,
    const float* __restrict__ py0, const float* __restrict__ pz0,
    const float* __restrict__ px1, const float* __restrict__ py1,
    const float* __restrict__ pz1, const float* __restrict__ px2,
    const float* __restrict__ py2, const float* __restrict__ pz2,
    float* __restrict__ out) {
  const int t = blockIdx.x * 256 + threadIdx.x;
  const int pt = t >> 4;
  const int cg = t & 15;
  if (pt >= NPTS) return;
  const float cx = (coords[pt * 3 + 0] + 1.0f) * 0.5f;
  const float cy = (coords[pt * 3 + 1] + 1.0f) * 0.5f;
  const float cz = (coords[pt * 3 + 2] + 1.0f) * 0.5f;
  const float* xs[3] = {px0, px1, px2};
  const float* ys[3] = {py0, py1, py2};
  const float* zs[3] = {pz0, pz1, pz2};
  const int sw[3] = {256, 128, 64};
  float* optr = out + (size_t)pt * 192 + cg * 4;
#pragma unroll
  for (int s = 0; s < 3; ++s) {
    const int W = sw[s];
    float4 acc = make_float4(0.f, 0.f, 0.f, 0.f);
    sample_acc_chw(xs[s], W, cx, cy, cg, acc);
    sample_acc_chw(ys[s], W, cy, cz, cg, acc);
    sample_acc_chw(zs[s], W, cx, cz, cg, acc);
    *reinterpret_cast<float4*>(optr + s * 64) = acc;
  }
}

// ---------------------------------------------------------------------------
extern "C" void kernel_launch(void* const* d_in, const int* in_sizes, int n_in,
                              void* d_out, int out_size, void* d_ws,
                              size_t ws_size, hipStream_t stream) {
  const float* coords = (const float*)d_in[0];
  const float* px0 = (const float*)d_in[1];
  const float* py0 = (const float*)d_in[2];
  const float* pz0 = (const float*)d_in[3];
  const float* px1 = (const float*)d_in[4];
  const float* py1 = (const float*)d_in[5];
  const float* pz1 = (const float*)d_in[6];
  const float* px2 = (const float*)d_in[7];
  const float* py2 = (const float*)d_in[8];
  const float* pz2 = (const float*)d_in[9];
  float* out = (float*)d_out;

  // ws layout (bytes): f16 planes, counts, end-cursor, weight records
  const size_t TP_BYTES = 33030144;
  const size_t CNT_OFF = TP_BYTES;           // 131072 B
  const size_t CUR_OFF = CNT_OFF + 131072;   // 131072 B
  const size_t REC_OFF = CUR_OFF + 131072;   // 48,000,000 B
  const size_t NEEDED = REC_OFF + (size_t)NPTS * 3 * 32;

  if (ws_size >= NEEDED) {
    __half* tp = (__half*)d_ws;
    int* counts = (int*)((char*)d_ws + CNT_OFF);
    int* cursor = (int*)((char*)d_ws + CUR_OFF);
    uint4* wrec = (uint4*)((char*)d_ws + REC_OFF);

    transpose_chw_hwc_f16<<<dim3(65536 / 64, 3), 256, 0, stream>>>(
        px0, py0, pz0, tp + 0, 65536);
    transpose_chw_hwc_f16<<<dim3(16384 / 64, 3), 256, 0, stream>>>(
        px1, py1, pz1, tp + 12582912, 16384);
    transpose_chw_hwc_f16<<<dim3(4096 / 64, 3), 256, 0, stream>>>(
        px2, py2, pz2, tp + 15728640, 4096);

    hipMemsetAsync(counts, 0, NBINS * sizeof(int), stream);
    const int pblocks = (NPTS + 255) / 256;
    bin_count<<<pblocks, 256, 0, stream>>>(coords, counts);
    bin_scan<<<1, 1024, 0, stream>>>(counts, cursor);
    bin_scatter_prep<<<pblocks, 256, 0, stream>>>(coords, cursor, wrec);
    // cursor[b] now == end offset of bin b

    sample_super<<<dim3(NSUPER, 3, 2), 256, 0, stream>>>(
        wrec, (const ushort*)tp, cursor, out);
  } else {
    const int sample_blocks = (NPTS * 16 + 255) / 256;
    sample_fallback<<<sample_blocks, 256, 0, stream>>>(
        coords, px0, py0, pz0, px1, py1, pz1, px2, py2, pz2, out);
  }
}

// Round 9
// 320.492 us; speedup vs baseline: 4.3653x; 1.0435x over previous
//
#include <hip/hip_runtime.h>
#include <hip/hip_fp16.h>

#define NPTS 500000
#define NBINS 32768   // 32^3 Morton bins
#define NSUPER 8192   // 4 bins merged (2x2 in x,y)
#define RSTRIDE 65    // padded row stride in uint4 (64 data + 1 pad)

// Planes stored fp16, pre-scaled by 1024 (exact pow2); final result * 1/1024.
#define PLANE_SCALE 1024.0f
#define INV_PLANE_SCALE 0.0009765625f

// ---------------------------------------------------------------------------
// Keys cubic conv weights, a = -0.75, taps at offsets [-1,0,1,2], t in [0,1)
// ---------------------------------------------------------------------------
__device__ __forceinline__ void cubic_w(float t, float w[4]) {
  const float a = -0.75f;
  const float t1 = t + 1.0f;
  w[0] = ((a * t1 - 5.0f * a) * t1 + 8.0f * a) * t1 - 4.0f * a;
  w[1] = ((a + 2.0f) * t - (a + 3.0f)) * t * t + 1.0f;
  const float u = 1.0f - t;
  w[2] = ((a + 2.0f) * u - (a + 3.0f)) * u * u + 1.0f;
  const float t2 = 2.0f - t;
  w[3] = ((a * t2 - 5.0f * a) * t2 + 8.0f * a) * t2 - 4.0f * a;
}

// ---------------------------------------------------------------------------
// Transpose (C,H,W) fp32 -> (H*W, C) fp16*1024, 3 planes batched on blockIdx.y
// ---------------------------------------------------------------------------
__global__ __launch_bounds__(256) void transpose_chw_hwc_f16(
    const float* __restrict__ p0, const float* __restrict__ p1,
    const float* __restrict__ p2, __half* __restrict__ dst, int HW) {
  __shared__ float lds[64][65];
  const float* src = (blockIdx.y == 0) ? p0 : ((blockIdx.y == 1) ? p1 : p2);
  __half* out = dst + (size_t)blockIdx.y * (size_t)HW * 64;
  const int pixBase = blockIdx.x * 64;
  const int tid = threadIdx.x;
  const int lane = tid & 63;
  const int quad = tid >> 6;
#pragma unroll
  for (int k = 0; k < 16; ++k) {
    const int c = k * 4 + quad;
    lds[c][lane] = src[(size_t)c * HW + pixBase + lane];
  }
  __syncthreads();
#pragma unroll
  for (int k = 0; k < 16; ++k) {
    const int pp = k * 4 + quad;
    out[(size_t)(pixBase + pp) * 64 + lane] =
        __float2half(lds[lane][pp] * PLANE_SCALE);
  }
}

// ---------------------------------------------------------------------------
// Morton binning helpers
// ---------------------------------------------------------------------------
__device__ __forceinline__ unsigned spread3(unsigned v) {
  return (v & 1u) | ((v & 2u) << 2) | ((v & 4u) << 4) | ((v & 8u) << 6) |
         ((v & 16u) << 8);
}

__device__ __forceinline__ unsigned compact3(unsigned v) {
  return (v & 1u) | ((v >> 2) & 2u) | ((v >> 4) & 4u) | ((v >> 6) & 8u) |
         ((v >> 8) & 16u);
}

__device__ __forceinline__ int bin_of(float cx, float cy, float cz) {
  int xq = (int)((cx + 1.0f) * 16.0f);
  int yq = (int)((cy + 1.0f) * 16.0f);
  int zq = (int)((cz + 1.0f) * 16.0f);
  xq = xq < 0 ? 0 : (xq > 31 ? 31 : xq);
  yq = yq < 0 ? 0 : (yq > 31 ? 31 : yq);
  zq = zq < 0 ? 0 : (zq > 31 ? 31 : zq);
  return (int)(spread3((unsigned)xq) | (spread3((unsigned)yq) << 1) |
               (spread3((unsigned)zq) << 2));
}

__global__ __launch_bounds__(256) void bin_count(
    const float* __restrict__ coords, int* __restrict__ counts) {
  const int pt = blockIdx.x * 256 + threadIdx.x;
  if (pt >= NPTS) return;
  const int b = bin_of(coords[pt * 3], coords[pt * 3 + 1], coords[pt * 3 + 2]);
  atomicAdd(&counts[b], 1);
}

__global__ __launch_bounds__(1024) void bin_scan(
    const int* __restrict__ counts, int* __restrict__ cursor) {
  __shared__ int lds[1024];
  const int t = threadIdx.x;
  const int base = t * 32;
  int s = 0;
#pragma unroll
  for (int i = 0; i < 32; ++i) s += counts[base + i];
  lds[t] = s;
  __syncthreads();
  int own = s;
  for (int off = 1; off < 1024; off <<= 1) {
    int v = (t >= off) ? lds[t - off] : 0;
    __syncthreads();
    lds[t] += v;
    __syncthreads();
  }
  int run = lds[t] - own;
#pragma unroll
  for (int i = 0; i < 32; ++i) {
    cursor[base + i] = run;
    run += counts[base + i];
  }
}

// ---------------------------------------------------------------------------
// Scatter fused with weight precompute. Per point, per scale, 32-B record:
// {wx01, wx23, wy01, wy23, wz01, wz23, relx*4|rely*4<<8|relz<<16, pt}
// rel are window-relative tap bases for the 2x2-merged superbin window.
// ---------------------------------------------------------------------------
__global__ __launch_bounds__(256) void bin_scatter_prep(
    const float* __restrict__ coords, int* __restrict__ cursor,
    uint4* __restrict__ wrec) {
  const int pt = blockIdx.x * 256 + threadIdx.x;
  if (pt >= NPTS) return;
  const float x = coords[pt * 3], y = coords[pt * 3 + 1],
              z = coords[pt * 3 + 2];
  const int b = bin_of(x, y, z);
  const int pos = atomicAdd(&cursor[b], 1);

  const int qx0 = ((int)compact3((unsigned)b)) & ~1;
  const int qy0 = ((int)compact3((unsigned)b >> 1)) & ~1;
  const int qz = (int)compact3((unsigned)b >> 2);
  const float vin[3] = {x, y, z};

#pragma unroll
  for (int s = 0; s < 3; ++s) {
    const int W = (s == 0) ? 256 : ((s == 1) ? 128 : 64);
    const float hw = 0.5f * (float)(W - 1);
    const int fb[3] = {(int)floorf((1.0f + (float)qx0 * 0.03125f) * hw),
                       (int)floorf((1.0f + (float)qy0 * 0.03125f) * hw),
                       (int)floorf((1.0f + (float)qz * 0.03125f) * hw)};
    uint wp[6];
    int rel[3];
#pragma unroll
    for (int a = 0; a < 3; ++a) {
      const float c = (vin[a] + 1.0f) * 0.5f;
      const float gx = (c + 1.0f) * 0.5f * (float)(W - 1);
      const float x0f = floorf(gx);
      float w[4];
      cubic_w(gx - x0f, w);
      int r = (int)x0f - fb[a];
      const int rmax = (a == 2) ? 4 : 12;
      r = r < 0 ? 0 : (r > rmax ? rmax : r);
      rel[a] = r;
      const __half2 lo = __halves2half2(__float2half(w[0]), __float2half(w[1]));
      const __half2 hi = __halves2half2(__float2half(w[2]), __float2half(w[3]));
      wp[a * 2] = *(const uint*)&lo;
      wp[a * 2 + 1] = *(const uint*)&hi;
    }
    uint4* dst = wrec + ((size_t)s * NPTS + pos) * 2;
    dst[0] = make_uint4(wp[0], wp[1], wp[2], wp[3]);
    dst[1] = make_uint4(
        wp[4], wp[5],
        (uint)(rel[0] * 4) | ((uint)(rel[1] * 4) << 8) | ((uint)rel[2] << 16),
        (uint)pt);
  }
}

// ---------------------------------------------------------------------------
// Superbin sampling: block per (superbin, scale, ch-half). 32 ch per block.
// LDS: 32 rows (XY 16y, YZ 8z, XZ 8z) x 16 cols x 4 cg, row stride 65 uint4
// (pad rotates bank-start per row: idx%8 = (row+relx4+cg)%8 -> ~2-way).
// Staging: one full row per wave per iter; wave-uniform LDS dest, linear.
// ---------------------------------------------------------------------------
__global__ __launch_bounds__(256, 4) void sample_super(
    const uint4* __restrict__ wrec, const ushort* __restrict__ tp,
    const int* __restrict__ endc, float* __restrict__ out) {
  __shared__ uint4 win[32 * RSTRIDE];

  const int orig = blockIdx.x;
  const int sb = (orig & 7) * (NSUPER / 8) + (orig >> 3);
  const int b0 = sb * 4;  // 4 consecutive Morton bins = 2x2 in (x,y)
  const int start = (b0 == 0) ? 0 : endc[b0 - 1];
  const int end = endc[b0 + 3];
  if (start >= end) return;

  const int s = blockIdx.y;
  const int h = blockIdx.z;  // channel half: 0 or 1
  const int W = (s == 0) ? 256 : ((s == 1) ? 128 : 64);
  const size_t sbase = (s == 0) ? 0 : ((s == 1) ? 12582912 : 15728640);
  const size_t psz = (size_t)W * W * 64;
  const float hw = 0.5f * (float)(W - 1);

  const int qx0 = ((int)compact3((unsigned)b0)) & ~1;
  const int qy0 = ((int)compact3((unsigned)b0 >> 1)) & ~1;
  const int qz = (int)compact3((unsigned)b0 >> 2);
  const int wbx = (int)floorf((1.0f + (float)qx0 * 0.03125f) * hw) - 1;
  const int wby = (int)floorf((1.0f + (float)qy0 * 0.03125f) * hw) - 1;
  const int wbz = (int)floorf((1.0f + (float)qz * 0.03125f) * hw) - 1;

  const char* tpb = (const char*)(tp + sbase) + h * 64;  // 32-ch half
  const int tid = threadIdx.x;
  const int wave = tid >> 6;
  const int lane = tid & 63;
  const int px = lane >> 2;      // 0..15 pixel within row
  const int cgl = lane & 3;      // 0..3 channel group
#pragma unroll
  for (int k = 0; k < 8; ++k) {
    const int row = k * 4 + wave;  // 0..31
    int p, grow, cb;
    if (row < 16) {
      p = 0;
      grow = wby + row;
      cb = wbx;
    } else if (row < 24) {
      p = 1;
      grow = wbz + row - 16;
      cb = wby;
    } else {
      p = 2;
      grow = wbz + row - 24;
      cb = wbx;
    }
    grow = grow < 0 ? 0 : (grow > W - 1 ? W - 1 : grow);
    int gcol = cb + px;
    gcol = gcol < 0 ? 0 : (gcol > W - 1 ? W - 1 : gcol);
    const char* src = tpb + (size_t)p * psz * 2 +
                      ((size_t)grow * W + gcol) * 128 + cgl * 16;
#if __has_builtin(__builtin_amdgcn_global_load_lds)
    __builtin_amdgcn_global_load_lds((const uint*)src,
                                     (uint*)&win[row * RSTRIDE], 16, 0, 0);
#else
    win[row * RSTRIDE + lane] = *reinterpret_cast<const uint4*>(src);
#endif
  }
  __syncthreads();

  const int lanegrp = tid >> 2;  // 64 point slots per block iteration
  const int cg = tid & 3;        // 8 channels per lane (of this 32-ch half)

  for (int i0 = start; i0 < end; i0 += 64) {
    const int slot = i0 + lanegrp;
    if (slot >= end) break;
    const uint4 r0 = wrec[((size_t)s * NPTS + slot) * 2];
    const uint4 r1 = wrec[((size_t)s * NPTS + slot) * 2 + 1];
    const int pt = (int)r1.w;
    const int relx4 = (int)(r1.z & 255u);         // rel_x * 4
    const int rely4 = (int)((r1.z >> 8) & 255u);  // rel_y * 4
    const int relz = (int)((r1.z >> 16) & 255u);
    const int rely = rely4 >> 2;

    // per-point LDS bases (uint4 units); +j*RSTRIDE folded as immediates
    const int xybase = rely * RSTRIDE + relx4 + cg;
    const int zrow = relz * RSTRIDE;
    const int yzbase = 16 * RSTRIDE + zrow + rely4 + cg;
    const int xzbase = 24 * RSTRIDE + zrow + relx4 + cg;

    __half2 wx[4], wy[4], wz[4];
    {
      const __half2 hx01 = *(const __half2*)&r0.x;
      const __half2 hx23 = *(const __half2*)&r0.y;
      const __half2 hy01 = *(const __half2*)&r0.z;
      const __half2 hy23 = *(const __half2*)&r0.w;
      const __half2 hz01 = *(const __half2*)&r1.x;
      const __half2 hz23 = *(const __half2*)&r1.y;
      wx[0] = __half2half2(__low2half(hx01));
      wx[1] = __half2half2(__high2half(hx01));
      wx[2] = __half2half2(__low2half(hx23));
      wx[3] = __half2half2(__high2half(hx23));
      wy[0] = __half2half2(__low2half(hy01));
      wy[1] = __half2half2(__high2half(hy01));
      wy[2] = __half2half2(__low2half(hy23));
      wy[3] = __half2half2(__high2half(hy23));
      wz[0] = __half2half2(__low2half(hz01));
      wz[1] = __half2half2(__high2half(hz01));
      wz[2] = __half2half2(__low2half(hz23));
      wz[3] = __half2half2(__high2half(hz23));
    }

    __half2 a0 = __float2half2_rn(0.0f), a1 = a0, a2 = a0, a3 = a0;

#define ROWTAPS(BASEPTR, CW, RW_j)                                    \
  {                                                                   \
    const uint4* bp = (BASEPTR);                                      \
    __half2 q0 = __float2half2_rn(0.0f), q1 = q0, q2 = q0, q3 = q0;   \
    _Pragma("unroll") for (int i = 0; i < 4; ++i) {                   \
      const uint4 v = bp[4 * i];                                      \
      q0 = __hfma2(CW[i], *(const __half2*)&v.x, q0);                 \
      q1 = __hfma2(CW[i], *(const __half2*)&v.y, q1);                 \
      q2 = __hfma2(CW[i], *(const __half2*)&v.z, q2);                 \
      q3 = __hfma2(CW[i], *(const __half2*)&v.w, q3);                 \
    }                                                                 \
    a0 = __hfma2(RW_j, q0, a0);                                       \
    a1 = __hfma2(RW_j, q1, a1);                                       \
    a2 = __hfma2(RW_j, q2, a2);                                       \
    a3 = __hfma2(RW_j, q3, a3);                                       \
  }

#pragma unroll
    for (int j = 0; j < 4; ++j)  // XY: row=y, col=x
      ROWTAPS(&win[xybase + j * RSTRIDE], wx, wy[j]);
#pragma unroll
    for (int j = 0; j < 4; ++j)  // YZ: row=z, col=y
      ROWTAPS(&win[yzbase + j * RSTRIDE], wy, wz[j]);
#pragma unroll
    for (int j = 0; j < 4; ++j)  // XZ: row=z, col=x
      ROWTAPS(&win[xzbase + j * RSTRIDE], wx, wz[j]);
#undef ROWTAPS

    const float2 f0 = __half22float2(a0);
    const float2 f1 = __half22float2(a1);
    const float2 f2 = __half22float2(a2);
    const float2 f3 = __half22float2(a3);
    float* optr = out + (size_t)pt * 192 + s * 64 + h * 32 + cg * 8;
    *reinterpret_cast<float4*>(optr) =
        make_float4(f0.x * INV_PLANE_SCALE, f0.y * INV_PLANE_SCALE,
                    f1.x * INV_PLANE_SCALE, f1.y * INV_PLANE_SCALE);
    *reinterpret_cast<float4*>(optr + 4) =
        make_float4(f2.x * INV_PLANE_SCALE, f2.y * INV_PLANE_SCALE,
                    f3.x * INV_PLANE_SCALE, f3.y * INV_PLANE_SCALE);
  }
}

// ---------------------------------------------------------------------------
// Fallback: fp32 direct from (C,H,W) if workspace too small.
// ---------------------------------------------------------------------------
__device__ __forceinline__ void sample_acc_chw(const float* __restrict__ plane,
                                               int W, float gx, float gy,
                                               int cg, float4& acc) {
  const float x = (gx + 1.0f) * 0.5f * (float)(W - 1);
  const float y = (gy + 1.0f) * 0.5f * (float)(W - 1);
  const float x0f = floorf(x), y0f = floorf(y);
  float wx[4], wy[4];
  cubic_w(x - x0f, wx);
  cubic_w(y - y0f, wy);
  const int x0 = (int)x0f, y0 = (int)y0f;
  int ix[4], iy[4];
#pragma unroll
  for (int i = 0; i < 4; ++i) {
    int xi = x0 - 1 + i;
    ix[i] = xi < 0 ? 0 : (xi > W - 1 ? W - 1 : xi);
    int yi = y0 - 1 + i;
    iy[i] = yi < 0 ? 0 : (yi > W - 1 ? W - 1 : yi);
  }
  const size_t HW = (size_t)W * W;
  float r[4] = {acc.x, acc.y, acc.z, acc.w};
#pragma unroll
  for (int cc = 0; cc < 4; ++cc) {
    const float* pc = plane + (size_t)(cg * 4 + cc) * HW;
    float a = 0.f;
#pragma unroll
    for (int j = 0; j < 4; ++j) {
      const float* rb = pc + (size_t)iy[j] * W;
      float row = 0.f;
#pragma unroll
      for (int i = 0; i < 4; ++i) row += wx[i] * rb[ix[i]];
      a += wy[j] * row;
    }
    r[cc] += a;
  }
  acc = make_float4(r[0], r[1], r[2], r[3]);
}

__global__ __launch_bounds__(256) void sample_fallback(
    const float* __restrict__ coords, const float* __restrict__ px0,
    const float* __restrict__ py0, const float* __restrict__ pz0,
    const float* __restrict__ px1, const float* __restrict__ py1,
    const float* __restrict__ pz1, const float* __restrict__ px2,
    const float* __restrict__ py2, const float* __restrict__ pz2,
    float* __restrict__ out) {
  const int t = blockIdx.x * 256 + threadIdx.x;
  const int pt = t >> 4;
  const int cg = t & 15;
  if (pt >= NPTS) return;
  const float cx = (coords[pt * 3 + 0] + 1.0f) * 0.5f;
  const float cy = (coords[pt * 3 + 1] + 1.0f) * 0.5f;
  const float cz = (coords[pt * 3 + 2] + 1.0f) * 0.5f;
  const float* xs[3] = {px0, px1, px2};
  const float* ys[3] = {py0, py1, py2};
  const float* zs[3] = {pz0, pz1, pz2};
  const int sw[3] = {256, 128, 64};
  float* optr = out + (size_t)pt * 192 + cg * 4;
#pragma unroll
  for (int s = 0; s < 3; ++s) {
    const int W = sw[s];
    float4 acc = make_float4(0.f, 0.f, 0.f, 0.f);
    sample_acc_chw(xs[s], W, cx, cy, cg, acc);
    sample_acc_chw(ys[s], W, cy, cz, cg, acc);
    sample_acc_chw(zs[s], W, cx, cz, cg, acc);
    *reinterpret_cast<float4*>(optr + s * 64) = acc;
  }
}

// ---------------------------------------------------------------------------
extern "C" void kernel_launch(void* const* d_in, const int* in_sizes, int n_in,
                              void* d_out, int out_size, void* d_ws,
                              size_t ws_size, hipStream_t stream) {
  const float* coords = (const float*)d_in[0];
  const float* px0 = (const float*)d_in[1];
  const float* py0 = (const float*)d_in[2];
  const float* pz0 = (const float*)d_in[3];
  const float* px1 = (const float*)d_in[4];
  const float* py1 = (const float*)d_in[5];
  const float* pz1 = (const float*)d_in[6];
  const float* px2 = (const float*)d_in[7];
  const float* py2 = (const float*)d_in[8];
  const float* pz2 = (const float*)d_in[9];
  float* out = (float*)d_out;

  // ws layout (bytes): f16 planes, counts, end-cursor, weight records
  const size_t TP_BYTES = 33030144;
  const size_t CNT_OFF = TP_BYTES;           // 131072 B
  const size_t CUR_OFF = CNT_OFF + 131072;   // 131072 B
  const size_t REC_OFF = CUR_OFF + 131072;   // 48,000,000 B
  const size_t NEEDED = REC_OFF + (size_t)NPTS * 3 * 32;

  if (ws_size >= NEEDED) {
    __half* tp = (__half*)d_ws;
    int* counts = (int*)((char*)d_ws + CNT_OFF);
    int* cursor = (int*)((char*)d_ws + CUR_OFF);
    uint4* wrec = (uint4*)((char*)d_ws + REC_OFF);

    transpose_chw_hwc_f16<<<dim3(65536 / 64, 3), 256, 0, stream>>>(
        px0, py0, pz0, tp + 0, 65536);
    transpose_chw_hwc_f16<<<dim3(16384 / 64, 3), 256, 0, stream>>>(
        px1, py1, pz1, tp + 12582912, 16384);
    transpose_chw_hwc_f16<<<dim3(4096 / 64, 3), 256, 0, stream>>>(
        px2, py2, pz2, tp + 15728640, 4096);

    hipMemsetAsync(counts, 0, NBINS * sizeof(int), stream);
    const int pblocks = (NPTS + 255) / 256;
    bin_count<<<pblocks, 256, 0, stream>>>(coords, counts);
    bin_scan<<<1, 1024, 0, stream>>>(counts, cursor);
    bin_scatter_prep<<<pblocks, 256, 0, stream>>>(coords, cursor, wrec);
    // cursor[b] now == end offset of bin b

    sample_super<<<dim3(NSUPER, 3, 2), 256, 0, stream>>>(
        wrec, (const ushort*)tp, cursor, out);
  } else {
    const int sample_blocks = (NPTS * 16 + 255) / 256;
    sample_fallback<<<sample_blocks, 256, 0, stream>>>(
        coords, px0, py0, pz0, px1, py1, pz1, px2, py2, pz2, out);
  }
}